// Round 4
// baseline (1017.557 us; speedup 1.0000x reference)
//
#include <hip/hip_runtime.h>
#include <hip/hip_bf16.h>
#include <math.h>

typedef __hip_bfloat16 bf16;
typedef short bf16x8 __attribute__((ext_vector_type(8)));
typedef float f32x4 __attribute__((ext_vector_type(4)));

#define NPIX 16384  // 128*128 spatial per channel

static __device__ __forceinline__ float ldv(float v) { return v; }
static __device__ __forceinline__ float ldv(bf16 v) { return __bfloat162float(v); }
static __device__ __forceinline__ float lds16(short s) {
    union { short s_; bf16 h; } u; u.s_ = s; return __bfloat162float(u.h);
}
template <typename T> static __device__ __forceinline__ T stv(float v);
template <> __device__ __forceinline__ float stv<float>(float v) { return v; }
template <> __device__ __forceinline__ bf16 stv<bf16>(float v) { return __float2bfloat16(v); }
static __device__ __forceinline__ short stv16(float v) {
    union { short s_; bf16 h; } u; u.h = __float2bfloat16(v); return u.s_;
}

static __device__ __forceinline__ unsigned pack2f(float a, float b) {
    union { bf16 h; unsigned short u; } ua, ub;
    ua.h = __float2bfloat16(a); ub.h = __float2bfloat16(b);
    return (unsigned)ua.u | ((unsigned)ub.u << 16);
}
static __device__ __forceinline__ unsigned packbb(unsigned short lo, unsigned short hi) {
    return (unsigned)lo | ((unsigned)hi << 16);
}

template <typename SrcT>
static __device__ __forceinline__ const SrcT* maprow(const SrcT* A, const SrcT* B, int k,
    int Ksplit, int agrp, int ags, int abss, int bgrp, int bgs, int bbs, int b)
{
    if (k < Ksplit) return A + (size_t)((k / agrp) * ags + b * abss + (k % agrp)) * NPIX;
    k -= Ksplit;
    return B + (size_t)((k / bgrp) * bgs + b * bbs + (k % bgrp)) * NPIX;
}

// ---------------------------------------------------------------------------
// Pack f32 weights -> bf16, flat. grid: n/2048, block 256.
// ---------------------------------------------------------------------------
__global__ __launch_bounds__(256) void packw(const float* __restrict__ s,
                                             bf16* __restrict__ d, int n)
{
    int i = (blockIdx.x * 256 + threadIdx.x) * 8;
    if (i + 8 > n) return;
    float4 v0 = *(const float4*)(s + i);
    float4 v1 = *(const float4*)(s + i + 4);
    uint4 u;
    u.x = pack2f(v0.x, v0.y); u.y = pack2f(v0.z, v0.w);
    u.z = pack2f(v1.x, v1.y); u.w = pack2f(v1.z, v1.w);
    *(uint4*)(void*)(d + i) = u;
}

// ---------------------------------------------------------------------------
// Transpose x [b][384][16384] f32 -> xT [b][16384][384] bf16.
// Tile 64 px x 384 ch via LDS with 16B-block XOR swizzle. grid: (256, 4)
// ---------------------------------------------------------------------------
__global__ __launch_bounds__(256) void xpose(const float* __restrict__ x,
                                             bf16* __restrict__ xT)
{
    __shared__ short Ls[64 * 384];
    const int t = threadIdx.x;
    const int px0 = blockIdx.x * 64;
    const int b = blockIdx.y;
    const float* xb = x + (size_t)b * 384 * NPIX;

#pragma unroll 4
    for (int i = 0; i < 24; ++i) {
        int e = i * 256 + t;
        int ch = e >> 4, seg = e & 15;
        float4 v = *(const float4*)(xb + (size_t)ch * NPIX + px0 + seg * 4);
        const float* vp = (const float*)&v;
#pragma unroll
        for (int j = 0; j < 4; ++j) {
            int px = seg * 4 + j;
            int B = (ch >> 3) ^ ((px >> 2) & 7);
            Ls[px * 384 + B * 8 + (ch & 7)] = stv16(vp[j]);
        }
    }
    __syncthreads();

    const int lpx = t >> 2;
    const int m = (lpx >> 2) & 7;
    bf16* ob = xT + ((size_t)b * NPIX + px0 + lpx) * 384;
#pragma unroll
    for (int j = 0; j < 12; ++j) {
        int B = (t & 3) + j * 4;
        bf16x8 blk = *(const bf16x8*)&Ls[lpx * 384 + (B ^ m) * 8];
        *(bf16x8*)(void*)(ob + B * 8) = blk;
    }
}

// ---------------------------------------------------------------------------
// Transpose bf16 ch-major [b][384][16K] -> px-major pxT[b][16K][768] upper half
// (ch offset +384). Same LDS swizzle as xpose. grid: (256, 4)
// ---------------------------------------------------------------------------
__global__ __launch_bounds__(256) void xposeB(const bf16* __restrict__ src,
                                              bf16* __restrict__ dst)
{
    __shared__ short Ls[64 * 384];
    const int t = threadIdx.x;
    const int px0 = blockIdx.x * 64;
    const int b = blockIdx.y;
    const bf16* sb = src + (size_t)b * 384 * NPIX;

#pragma unroll 4
    for (int i = 0; i < 12; ++i) {
        int e = i * 256 + t;               // 3072 x 16B loads
        int ch = e >> 3, seg = e & 7;
        bf16x8 v = *(const bf16x8*)(const void*)(sb + (size_t)ch * NPIX + px0 + seg * 8);
#pragma unroll
        for (int j = 0; j < 8; ++j) {
            int px = seg * 8 + j;
            int B = (ch >> 3) ^ ((px >> 2) & 7);
            Ls[px * 384 + B * 8 + (ch & 7)] = v[j];
        }
    }
    __syncthreads();

    const int lpx = t >> 2;
    const int m = (lpx >> 2) & 7;
    bf16* ob = dst + ((size_t)b * NPIX + px0 + lpx) * 768 + 384;
#pragma unroll
    for (int j = 0; j < 12; ++j) {
        int B = (t & 3) + j * 4;
        bf16x8 blk = *(const bf16x8*)&Ls[lpx * 384 + (B ^ m) * 8];
        *(bf16x8*)(void*)(ob + B * 8) = blk;
    }
}

// ---------------------------------------------------------------------------
// gemmT2: all-direct-from-global MFMA GEMM. A = packed bf16 weights (row
// stride K), B = px-major bf16 (row stride K). No LDS, no barriers.
// Unroll-2 register rotation (aA/bA, aB/bB) -> true prefetch, no reg copies.
// BM=48, BN=256, 4 waves x (3x4) 16x16 tiles. XCD-swizzled 1D grid.
// grid: bmCount * 64 * 4
// ---------------------------------------------------------------------------
template <int K, typename OutT>
__global__ __launch_bounds__(256) void gemmT2(
    const bf16* __restrict__ wp, int wMod, int wsA, int wsB, int wrow0,
    const bf16* __restrict__ bsrc,
    OutT* __restrict__ out, int oMod, int osA, int osB, int obS, int orow0,
    int bmCount)
{
    const int t = threadIdx.x;
    const int gid = blockIdx.x;
    const int xcd = gid & 7, mm = gid >> 3;
    const int bm = mm % bmCount, gl = mm / bmCount;
    const int g = gl * 8 + xcd;
    const int b = g & 3, p0 = (g >> 2) * 256;

    const int l = t & 63, wvid = t >> 6, l15 = l & 15, q = l >> 4;
    const int arow = wrow0 + (bm % wMod) * wsA + (bm / wMod) * wsB;

    const bf16* ap = wp + (size_t)(arow + l15) * K + q * 8;
    const bf16* bp = bsrc + ((size_t)b * NPIX + p0 + wvid * 64 + l15) * K + q * 8;

    f32x4 acc[3][4];
#pragma unroll
    for (int mt = 0; mt < 3; ++mt)
#pragma unroll
        for (int nt = 0; nt < 4; ++nt) acc[mt][nt] = (f32x4){0.f, 0.f, 0.f, 0.f};

    bf16x8 aA[3], aB[3], bA[4], bB[4];
#pragma unroll
    for (int mt = 0; mt < 3; ++mt) {
        aA[mt] = *(const bf16x8*)(const void*)(ap + (size_t)mt * 16 * K);
        aB[mt] = *(const bf16x8*)(const void*)(ap + (size_t)mt * 16 * K + 32);
    }
#pragma unroll
    for (int nt = 0; nt < 4; ++nt) {
        bA[nt] = *(const bf16x8*)(const void*)(bp + (size_t)nt * 16 * K);
        bB[nt] = *(const bf16x8*)(const void*)(bp + (size_t)nt * 16 * K + 32);
    }

#pragma unroll
    for (int kk = 0; kk < K; kk += 64) {
#pragma unroll
        for (int mt = 0; mt < 3; ++mt)
#pragma unroll
            for (int nt = 0; nt < 4; ++nt)
                acc[mt][nt] = __builtin_amdgcn_mfma_f32_16x16x32_bf16(
                    aA[mt], bA[nt], acc[mt][nt], 0, 0, 0);
        if (kk + 64 < K) {
#pragma unroll
            for (int mt = 0; mt < 3; ++mt)
                aA[mt] = *(const bf16x8*)(const void*)(ap + (size_t)mt * 16 * K + kk + 64);
#pragma unroll
            for (int nt = 0; nt < 4; ++nt)
                bA[nt] = *(const bf16x8*)(const void*)(bp + (size_t)nt * 16 * K + kk + 64);
        }
#pragma unroll
        for (int mt = 0; mt < 3; ++mt)
#pragma unroll
            for (int nt = 0; nt < 4; ++nt)
                acc[mt][nt] = __builtin_amdgcn_mfma_f32_16x16x32_bf16(
                    aB[mt], bB[nt], acc[mt][nt], 0, 0, 0);
        if (kk + 96 < K) {
#pragma unroll
            for (int mt = 0; mt < 3; ++mt)
                aB[mt] = *(const bf16x8*)(const void*)(ap + (size_t)mt * 16 * K + kk + 96);
#pragma unroll
            for (int nt = 0; nt < 4; ++nt)
                bB[nt] = *(const bf16x8*)(const void*)(bp + (size_t)nt * 16 * K + kk + 96);
        }
    }

    const int obase = orow0 + (bm % oMod) * osA + (bm / oMod) * osB + b * obS;
#pragma unroll
    for (int mt = 0; mt < 3; ++mt)
#pragma unroll
        for (int nt = 0; nt < 4; ++nt)
#pragma unroll
            for (int r = 0; r < 4; ++r) {
                int row = obase + mt * 16 + q * 4 + r;
                int col = p0 + wvid * 64 + nt * 16 + l15;
                out[(size_t)row * NPIX + col] = stv<OutT>(acc[mt][nt][r]);
            }
}

// ---------------------------------------------------------------------------
// Pipelined MFMA pointwise GEMM (kept for LITE/ULTRA fallback paths)
// ---------------------------------------------------------------------------
template <typename SrcT, typename OutT>
__global__ __launch_bounds__(256) void gemm48(
    const SrcT* __restrict__ srcA, const SrcT* __restrict__ srcB, int Ksplit, int K,
    int agrp, int ags, int abss, int bgrp, int bgs, int bbs,
    const float* __restrict__ w, int wMod, int wsA, int wsB, int wrow0,
    OutT* __restrict__ out, int oMod, int osA, int osB, int obS, int orow0)
{
    __shared__ __align__(16) short As[2][48 * 40];
    __shared__ __align__(16) short Bs[2][128 * 40];

    const int t  = threadIdx.x;
    const int bm = blockIdx.x;
    const int p0 = blockIdx.y * 128;
    const int b  = blockIdx.z;

    const int l = t & 63, wvid = t >> 6, l15 = l & 15, q = l >> 4;
    const int c4 = t >> 4, rp = t & 15;

    const int wbase = wrow0 + (bm % wMod) * wsA + (bm / wMod) * wsB;

    f32x4 acc[3][2];
#pragma unroll
    for (int mt = 0; mt < 3; ++mt)
#pragma unroll
        for (int nt = 0; nt < 2; ++nt) acc[mt][nt] = (f32x4){0.f, 0.f, 0.f, 0.f};

    float aw[6];
    float fb[16];
    bf16x8 hA, hB;

    auto LOADA = [&](int k0) {
#pragma unroll
        for (int i = 0; i < 3; ++i) {
            int idx = t + i * 256, row = idx >> 4, kq = idx & 15;
            float2 v = *(const float2*)(w + (size_t)(wbase + row) * K + k0 + kq * 2);
            aw[2 * i] = v.x; aw[2 * i + 1] = v.y;
        }
    };
    auto STOREA = [&](int buf) {
#pragma unroll
        for (int i = 0; i < 3; ++i) {
            int idx = t + i * 256, row = idx >> 4, kq = idx & 15;
            *(unsigned*)&As[buf][row * 40 + kq * 2] = pack2f(aw[2 * i], aw[2 * i + 1]);
        }
    };
    auto LOADB = [&](int k0) {
        const SrcT* r0 = maprow(srcA, srcB, k0 + 2 * rp,     Ksplit, agrp, ags, abss, bgrp, bgs, bbs, b) + p0 + c4 * 8;
        const SrcT* r1 = maprow(srcA, srcB, k0 + 2 * rp + 1, Ksplit, agrp, ags, abss, bgrp, bgs, bbs, b) + p0 + c4 * 8;
        if constexpr (sizeof(SrcT) == 4) {
            float4 a0 = *(const float4*)r0, a1 = *(const float4*)(r0 + 4);
            float4 b0 = *(const float4*)r1, b1 = *(const float4*)(r1 + 4);
            fb[0] = a0.x; fb[1] = a0.y; fb[2] = a0.z; fb[3] = a0.w;
            fb[4] = a1.x; fb[5] = a1.y; fb[6] = a1.z; fb[7] = a1.w;
            fb[8] = b0.x; fb[9] = b0.y; fb[10] = b0.z; fb[11] = b0.w;
            fb[12] = b1.x; fb[13] = b1.y; fb[14] = b1.z; fb[15] = b1.w;
        } else {
            hA = *(const bf16x8*)(const void*)r0;
            hB = *(const bf16x8*)(const void*)r1;
        }
    };
    auto STOREB = [&](int buf) {
#pragma unroll
        for (int j = 0; j < 8; ++j) {
            unsigned d;
            if constexpr (sizeof(SrcT) == 4) d = pack2f(fb[j], fb[8 + j]);
            else d = packbb((unsigned short)hA[j], (unsigned short)hB[j]);
            *(unsigned*)&Bs[buf][(c4 * 8 + j) * 40 + rp * 2] = d;
        }
    };

    LOADA(0); LOADB(0);
    STOREA(0); STOREB(0);
    const int S = K / 32;
    for (int s = 0; s < S; ++s) {
        const int cur = s & 1;
        __syncthreads();
        if (s + 1 < S) { LOADA((s + 1) * 32); LOADB((s + 1) * 32); }
        bf16x8 af[3], bfr[2];
#pragma unroll
        for (int mt = 0; mt < 3; ++mt)
            af[mt] = *(const bf16x8*)&As[cur][(mt * 16 + l15) * 40 + q * 8];
#pragma unroll
        for (int nt = 0; nt < 2; ++nt)
            bfr[nt] = *(const bf16x8*)&Bs[cur][(wvid * 32 + nt * 16 + l15) * 40 + q * 8];
#pragma unroll
        for (int mt = 0; mt < 3; ++mt)
#pragma unroll
            for (int nt = 0; nt < 2; ++nt)
                acc[mt][nt] = __builtin_amdgcn_mfma_f32_16x16x32_bf16(
                    af[mt], bfr[nt], acc[mt][nt], 0, 0, 0);
        if (s + 1 < S) { STOREA(1 - cur); STOREB(1 - cur); }
    }

    const int obase = orow0 + (bm % oMod) * osA + (bm / oMod) * osB + b * obS;
#pragma unroll
    for (int mt = 0; mt < 3; ++mt)
#pragma unroll
        for (int nt = 0; nt < 2; ++nt)
#pragma unroll
            for (int r = 0; r < 4; ++r) {
                int row = obase + mt * 16 + q * 4 + r;
                int col = p0 + wvid * 32 + nt * 16 + l15;
                out[(size_t)row * NPIX + col] = stv<OutT>(acc[mt][nt][r]);
            }
}

// ---------------------------------------------------------------------------
// Vectorized depthwise 3x3 (+optional exact GELU). 8 px/thread, b128 loads.
// ---------------------------------------------------------------------------
__global__ __launch_bounds__(256) void dw3x3v(
    const bf16* __restrict__ in, const float* __restrict__ w, bf16* __restrict__ out,
    int isQkv, int whofs, int inB, int ig, int outB, int og, int obase, int applyGelu)
{
    const int t = threadIdx.x;
    const int g = blockIdx.x * 256 + t;
    const int c = blockIdx.y;
    const int b = blockIdx.z;
    const int y = g >> 4;
    const int x0 = (g & 15) * 8;

    int inRow, wch, outRow;
    if (isQkv) {
        int h = c / 144, r = c - h * 144;
        inRow  = h * ig + b * inB + r;
        wch    = (r / 48) * 384 + h * 48 + whofs + (r % 48);
        outRow = h * og + b * outB + r + obase;
    } else {
        inRow = b * inB + c; wch = c; outRow = b * outB + c;
    }

    const bf16* ib = in + (size_t)inRow * NPIX;
    float wv[9];
#pragma unroll
    for (int i = 0; i < 9; ++i) wv[i] = w[wch * 9 + i];

    float vv[3][10];
#pragma unroll
    for (int dy = 0; dy < 3; ++dy) {
        int yy = y + dy - 1;
        if (yy < 0 || yy > 127) {
#pragma unroll
            for (int j = 0; j < 10; ++j) vv[dy][j] = 0.f;
        } else {
            const bf16* rb = ib + yy * 128;
            bf16x8 m = *(const bf16x8*)(const void*)(rb + x0);
#pragma unroll
            for (int j = 0; j < 8; ++j) vv[dy][j + 1] = lds16(m[j]);
            vv[dy][0] = (x0 > 0)   ? ldv(rb[x0 - 1]) : 0.f;
            vv[dy][9] = (x0 < 120) ? ldv(rb[x0 + 8]) : 0.f;
        }
    }
    bf16x8 res;
#pragma unroll
    for (int j = 0; j < 8; ++j) {
        float a = 0.f;
#pragma unroll
        for (int dy = 0; dy < 3; ++dy)
#pragma unroll
            for (int dx = 0; dx < 3; ++dx)
                a += wv[dy * 3 + dx] * vv[dy][j + dx];
        if (applyGelu) a = 0.5f * a * (1.0f + erff(a * 0.70710678118654752f));
        res[j] = stv16(a);
    }
    *(bf16x8*)(void*)(out + (size_t)outRow * NPIX + y * 128 + x0) = res;
}

// ---------------------------------------------------------------------------
// inv-L2-norm, vectorized. grid: 2*NBH*48 blocks over qkvd [bh][144][p].
// ---------------------------------------------------------------------------
__global__ __launch_bounds__(256) void l2norm_v(const bf16* __restrict__ qkvd,
                                                float* __restrict__ inv, int NBH)
{
    const int id = blockIdx.x;
    const int which = id / (NBH * 48);
    const int rem = id - which * NBH * 48;
    const int bh = rem / 48, c = rem - bh * 48;
    const bf16* base = qkvd + (size_t)(bh * 144 + which * 48 + c) * NPIX;

    float s = 0.f;
#pragma unroll
    for (int it = 0; it < 8; ++it) {
        bf16x8 v = *(const bf16x8*)(const void*)(base + ((size_t)threadIdx.x + it * 256) * 8);
#pragma unroll
        for (int j = 0; j < 8; ++j) { float f = lds16(v[j]); s += f * f; }
    }
#pragma unroll
    for (int off = 32; off; off >>= 1) s += __shfl_down(s, off, 64);
    __shared__ float partial[4];
    if ((threadIdx.x & 63) == 0) partial[threadIdx.x >> 6] = s;
    __syncthreads();
    if (threadIdx.x == 0) {
        float tt = partial[0] + partial[1] + partial[2] + partial[3];
        inv[(which * NBH + bh) * 48 + c] = 1.0f / fmaxf(sqrtf(tt), 1e-12f);
    }
}

// ---------------------------------------------------------------------------
// QK^T logits partials via MFMA, direct-from-global fragments.
// ---------------------------------------------------------------------------
__global__ __launch_bounds__(256) void qk_mfma(const bf16* __restrict__ qkvd,
                                               float* __restrict__ lp, int NBH, int pxs)
{
    const int bh = blockIdx.x;
    const int wvid = threadIdx.x >> 6;
    const int slice = blockIdx.y * 4 + wvid;
    const int l = threadIdx.x & 63, l15 = l & 15, q = l >> 4;

    const bf16* qb = qkvd + (size_t)(bh * 144) * NPIX;
    const bf16* kb = qb + (size_t)48 * NPIX;

    f32x4 acc[3][3];
#pragma unroll
    for (int mt = 0; mt < 3; ++mt)
#pragma unroll
        for (int nt = 0; nt < 3; ++nt) acc[mt][nt] = (f32x4){0.f, 0.f, 0.f, 0.f};

    const int pbeg = slice * pxs;
    for (int kk = 0; kk < pxs; kk += 32) {
        const int pc = pbeg + kk + q * 8;
        bf16x8 af[3], bfv[3];
#pragma unroll
        for (int mt = 0; mt < 3; ++mt)
            af[mt] = *(const bf16x8*)(const void*)(qb + (size_t)(mt * 16 + l15) * NPIX + pc);
#pragma unroll
        for (int nt = 0; nt < 3; ++nt)
            bfv[nt] = *(const bf16x8*)(const void*)(kb + (size_t)(nt * 16 + l15) * NPIX + pc);
#pragma unroll
        for (int mt = 0; mt < 3; ++mt)
#pragma unroll
            for (int nt = 0; nt < 3; ++nt)
                acc[mt][nt] = __builtin_amdgcn_mfma_f32_16x16x32_bf16(
                    af[mt], bfv[nt], acc[mt][nt], 0, 0, 0);
    }
    float* o = lp + ((size_t)slice * NBH + bh) * 2304;
#pragma unroll
    for (int mt = 0; mt < 3; ++mt)
#pragma unroll
        for (int nt = 0; nt < 3; ++nt)
#pragma unroll
            for (int r = 0; r < 4; ++r)
                o[(mt * 16 + q * 4 + r) * 48 + nt * 16 + l15] = acc[mt][nt][r];
}

// ---------------------------------------------------------------------------
// Sum NSL slice-partials, apply scale*invq*invk, row-softmax, emit bf16.
// ---------------------------------------------------------------------------
__global__ __launch_bounds__(256) void softmax48(const float* __restrict__ lp,
                                                 const float* __restrict__ inv,
                                                 bf16* __restrict__ a_bf, int NBH, int NSL)
{
    const int bh = blockIdx.x, t = threadIdx.x;
    __shared__ float L[2304];
    for (int e = t; e < 2304; e += 256) {
        float s = 0.f;
        for (int sl = 0; sl < NSL; ++sl) s += lp[((size_t)sl * NBH + bh) * 2304 + e];
        int i = e / 48, j = e - i * 48;
        L[e] = s * 0.14433756729740643f * inv[bh * 48 + i] * inv[(NBH + bh) * 48 + j];
    }
    __syncthreads();
    if (t < 48) {
        float m = -1e30f;
#pragma unroll
        for (int j = 0; j < 48; ++j) m = fmaxf(m, L[t * 48 + j]);
        float e_[48]; float ssum = 0.f;
#pragma unroll
        for (int j = 0; j < 48; ++j) { e_[j] = expf(L[t * 48 + j] - m); ssum += e_[j]; }
        float r = 1.f / ssum;
        bf16* ab = a_bf + (size_t)bh * 3072 + t * 64;
#pragma unroll
        for (int j = 0; j < 48; ++j) ab[j] = stv<bf16>(e_[j] * r);
#pragma unroll
        for (int j = 48; j < 64; ++j) ab[j] = stv<bf16>(0.f);
    }
}

// ---------------------------------------------------------------------------
// AV via MFMA, ch-major output (LITE/ULTRA paths).
// ---------------------------------------------------------------------------
__global__ __launch_bounds__(256) void av_mfma(const bf16* __restrict__ a_bf,
                                               const bf16* __restrict__ qkvd,
                                               bf16* __restrict__ out, int obase, int oS)
{
    __shared__ __align__(16) short Bs[128 * 72];
    const int t = threadIdx.x;
    const int px0 = blockIdx.x * 128;
    const int bh = blockIdx.y;
    const int l = t & 63, wvid = t >> 6, l15 = l & 15, q = l >> 4;
    const int c4 = t >> 4, rp = t & 15;

    const bf16* ab = a_bf + (size_t)bh * 3072;
    bf16x8 af[3][2];
#pragma unroll
    for (int mt = 0; mt < 3; ++mt)
#pragma unroll
        for (int kq = 0; kq < 2; ++kq)
            af[mt][kq] = *(const bf16x8*)(const void*)(ab + (mt * 16 + l15) * 64 + kq * 32 + q * 8);

    const bf16* vb = qkvd + (size_t)(bh * 144 + 96) * NPIX;
    bf16x8 vr[4];
#pragma unroll
    for (int jj = 0; jj < 4; ++jj) {
        int j = rp * 4 + jj; int jc = j < 48 ? j : 47;
        vr[jj] = *(const bf16x8*)(const void*)(vb + (size_t)jc * NPIX + px0 + c4 * 8);
    }
#pragma unroll
    for (int j = 0; j < 8; ++j) {
        *(unsigned*)&Bs[(c4 * 8 + j) * 72 + rp * 4]     = packbb((unsigned short)vr[0][j], (unsigned short)vr[1][j]);
        *(unsigned*)&Bs[(c4 * 8 + j) * 72 + rp * 4 + 2] = packbb((unsigned short)vr[2][j], (unsigned short)vr[3][j]);
    }
    __syncthreads();

    f32x4 acc[3][2];
#pragma unroll
    for (int mt = 0; mt < 3; ++mt)
#pragma unroll
        for (int nt = 0; nt < 2; ++nt) acc[mt][nt] = (f32x4){0.f, 0.f, 0.f, 0.f};

    bf16x8 bfv[2][2];
#pragma unroll
    for (int nt = 0; nt < 2; ++nt)
#pragma unroll
        for (int kq = 0; kq < 2; ++kq)
            bfv[nt][kq] = *(const bf16x8*)&Bs[(wvid * 32 + nt * 16 + l15) * 72 + kq * 32 + q * 8];
#pragma unroll
    for (int kq = 0; kq < 2; ++kq)
#pragma unroll
        for (int mt = 0; mt < 3; ++mt)
#pragma unroll
            for (int nt = 0; nt < 2; ++nt)
                acc[mt][nt] = __builtin_amdgcn_mfma_f32_16x16x32_bf16(
                    af[mt][kq], bfv[nt][kq], acc[mt][nt], 0, 0, 0);
#pragma unroll
    for (int mt = 0; mt < 3; ++mt)
#pragma unroll
        for (int nt = 0; nt < 2; ++nt)
#pragma unroll
            for (int r = 0; r < 4; ++r) {
                int row = obase + bh * oS + mt * 16 + q * 4 + r;
                int col = px0 + wvid * 32 + nt * 16 + l15;
                out[(size_t)row * NPIX + col] = stv<bf16>(acc[mt][nt][r]);
            }
}

// ---------------------------------------------------------------------------
// AV via MFMA, px-major output into pxT[b][16K][768] lower half (ch h*48+c).
// grid: (128, NBH=32)
// ---------------------------------------------------------------------------
__global__ __launch_bounds__(256) void av_mfma2(const bf16* __restrict__ a_bf,
                                                const bf16* __restrict__ qkvd,
                                                bf16* __restrict__ pxT)
{
    __shared__ __align__(16) short Bs[128 * 72];
    const int t = threadIdx.x;
    const int px0 = blockIdx.x * 128;
    const int bh = blockIdx.y;
    const int l = t & 63, wvid = t >> 6, l15 = l & 15, q = l >> 4;
    const int c4 = t >> 4, rp = t & 15;

    const bf16* ab = a_bf + (size_t)bh * 3072;
    bf16x8 af[3][2];
#pragma unroll
    for (int mt = 0; mt < 3; ++mt)
#pragma unroll
        for (int kq = 0; kq < 2; ++kq)
            af[mt][kq] = *(const bf16x8*)(const void*)(ab + (mt * 16 + l15) * 64 + kq * 32 + q * 8);

    const bf16* vb = qkvd + (size_t)(bh * 144 + 96) * NPIX;
    bf16x8 vr[4];
#pragma unroll
    for (int jj = 0; jj < 4; ++jj) {
        int j = rp * 4 + jj; int jc = j < 48 ? j : 47;
        vr[jj] = *(const bf16x8*)(const void*)(vb + (size_t)jc * NPIX + px0 + c4 * 8);
    }
#pragma unroll
    for (int j = 0; j < 8; ++j) {
        *(unsigned*)&Bs[(c4 * 8 + j) * 72 + rp * 4]     = packbb((unsigned short)vr[0][j], (unsigned short)vr[1][j]);
        *(unsigned*)&Bs[(c4 * 8 + j) * 72 + rp * 4 + 2] = packbb((unsigned short)vr[2][j], (unsigned short)vr[3][j]);
    }
    __syncthreads();

    f32x4 acc[3][2];
#pragma unroll
    for (int mt = 0; mt < 3; ++mt)
#pragma unroll
        for (int nt = 0; nt < 2; ++nt) acc[mt][nt] = (f32x4){0.f, 0.f, 0.f, 0.f};

    bf16x8 bfv[2][2];
#pragma unroll
    for (int nt = 0; nt < 2; ++nt)
#pragma unroll
        for (int kq = 0; kq < 2; ++kq)
            bfv[nt][kq] = *(const bf16x8*)&Bs[(wvid * 32 + nt * 16 + l15) * 72 + kq * 32 + q * 8];
#pragma unroll
    for (int kq = 0; kq < 2; ++kq)
#pragma unroll
        for (int mt = 0; mt < 3; ++mt)
#pragma unroll
            for (int nt = 0; nt < 2; ++nt)
                acc[mt][nt] = __builtin_amdgcn_mfma_f32_16x16x32_bf16(
                    af[mt][kq], bfv[nt][kq], acc[mt][nt], 0, 0, 0);

    // transpose acc -> Bs[pxl][48ch] bf16, then coalesced px-major stores
    __syncthreads();
#pragma unroll
    for (int mt = 0; mt < 3; ++mt)
#pragma unroll
        for (int nt = 0; nt < 2; ++nt) {
            int pxl = wvid * 32 + nt * 16 + l15;
#pragma unroll
            for (int r = 0; r < 2; ++r)
                *(unsigned*)&Bs[pxl * 48 + mt * 16 + q * 4 + r * 2] =
                    pack2f(acc[mt][nt][2 * r], acc[mt][nt][2 * r + 1]);
        }
    __syncthreads();

    const int h = bh >> 2, bb = bh & 3;
    const int pxl = t >> 1, half = t & 1;
    bf16* ob = pxT + ((size_t)bb * NPIX + px0 + pxl) * 768 + h * 48 + half * 24;
#pragma unroll
    for (int j = 0; j < 3; ++j)
        *(bf16x8*)(void*)(ob + j * 8) = *(const bf16x8*)&Bs[pxl * 48 + half * 24 + j * 8];
}

// ---------------------------------------------------------------------------
extern "C" void kernel_launch(void* const* d_in, const int* in_sizes, int n_in,
                              void* d_out, int out_size, void* d_ws, size_t ws_size,
                              hipStream_t stream) {
    const float* x       = (const float*)d_in[0];
    const float* w_qkv   = (const float*)d_in[1];
    const float* w_dw    = (const float*)d_in[2];
    const float* w_proj  = (const float*)d_in[3];
    const float* w_bs_pw = (const float*)d_in[4];
    const float* w_bs_dw = (const float*)d_in[5];
    float* out = (float*)d_out;
    bf16* y1 = (bf16*)d_out;  // bs_pw bf16 output lives in d_out space until proj

    const size_t SZQ = 150994944ull;  // 8h*4b*144*16384*2
    const size_t SZH = 18874368ull;   // 4b*144*16384*2
    const size_t SZY = 50331648ull;   // 4b*384*16384*2
    const size_t SZPXT = 100663296ull; // 4b*16384*768*2
    char* ws = (char*)d_ws;
    dim3 blk(256);

    if (ws_size >= 371404800ull) {
        // ---------- FULL: all heads batched ----------
        // ws[0..151M]: qkvp (steps 4-5) then pxT[4][16K][768] (96M, steps 9+);
        //              wprojp at ws+SZPXT (after pxT end, inside dead qkvp)
        // ws[151..302M]: qkvd
        // ws[302..352M]: xT (steps 3-7) then yg (steps 8-9)
        // ws[352..371M]: lp (hosts wqkvp+wbsp until qk clobbers)
        bf16* qkvp = (bf16*)ws;
        bf16* pxT  = (bf16*)ws;
        bf16* wprojp = (bf16*)(ws + SZPXT);           // FIX: was ws+80MB, inside pxT
        bf16* qkvd = (bf16*)(ws + SZQ);
        bf16* xT   = (bf16*)(ws + 2 * SZQ);
        bf16* yg   = xT;
        float* lp  = (float*)(ws + 2 * SZQ + SZY);
        bf16* wqkvp = (bf16*)lp;
        bf16* wbsp  = (bf16*)((char*)lp + 884736ull);
        bf16* abf  = (bf16*)(ws + 2 * SZQ + SZY + 18874368ull);
        float* inv = (float*)(ws + 2 * SZQ + SZY + 18874368ull + 196608ull);

        packw<<<dim3(216), blk, 0, stream>>>(w_qkv, wqkvp, 442368);
        packw<<<dim3(72), blk, 0, stream>>>(w_bs_pw, wbsp, 147456);
        xpose<<<dim3(256, 4), blk, 0, stream>>>(x, xT);
        gemmT2<384, bf16><<<dim3(24 * 256), blk, 0, stream>>>(
            wqkvp, 3, 384, 48, 0, xT, qkvp, 3, 48, 576, 144, 0, 24);
        dw3x3v<<<dim3(8, 1152, 4), blk, 0, stream>>>(
            qkvp, w_dw, qkvd, 1, 0, 144, 576, 144, 576, 0, 0);
        packw<<<dim3(144), blk, 0, stream>>>(w_proj, wprojp, 294912);  // qkvp dead
        gemmT2<384, bf16><<<dim3(8 * 256), blk, 0, stream>>>(
            wbsp, 1, 0, 48, 0, xT, y1, 1, 0, 48, 384, 0, 8);
        dw3x3v<<<dim3(8, 384, 4), blk, 0, stream>>>(
            y1, w_bs_dw, yg, 0, 0, 384, 0, 384, 0, 0, 1);          // xT dead, yg over it
        xposeB<<<dim3(256, 4), blk, 0, stream>>>(yg, pxT);         // yg -> pxT[.., 384:768]
        l2norm_v<<<dim3(2 * 32 * 48), blk, 0, stream>>>(qkvd, inv, 32);
        qk_mfma<<<dim3(32, 16), blk, 0, stream>>>(qkvd, lp, 32, 256);
        softmax48<<<dim3(32), blk, 0, stream>>>(lp, inv, abf, 32, 64);
        av_mfma2<<<dim3(128, 32), blk, 0, stream>>>(abf, qkvd, pxT); // -> pxT[.., 0:384]
        gemmT2<768, float><<<dim3(8 * 256), blk, 0, stream>>>(
            wprojp, 1, 0, 48, 0, pxT, out, 1, 0, 48, 384, 0, 8);
    } else if (ws_size >= 239284224ull) {
        // ---------- LITE: per-head pw+dw, rest batched ----------
        bf16* qkvd = (bf16*)ws;
        bf16* qph  = (bf16*)(ws + SZQ);
        bf16* yg   = (bf16*)(ws + SZQ + SZH);
        float* lp  = (float*)(ws + SZQ + SZH + SZY);
        bf16* abf  = (bf16*)(ws + SZQ + SZH + SZY + 18874368ull);
        float* inv = (float*)(ws + SZQ + SZH + SZY + 18874368ull + 196608ull);

        for (int h = 0; h < 8; ++h) {
            gemm48<float, bf16><<<dim3(3, 128, 4), blk, 0, stream>>>(
                x, x, 384, 384, 384, 0, 384, 384, 0, 384,
                w_qkv, 3, 384, 48, h * 48, qph, 3, 48, 0, 144, 0);
            dw3x3v<<<dim3(8, 144, 4), blk, 0, stream>>>(
                qph, w_dw, qkvd, 1, h * 48, 144, 0, 144, 0, h * 576, 0);
        }
        l2norm_v<<<dim3(2 * 32 * 48), blk, 0, stream>>>(qkvd, inv, 32);
        qk_mfma<<<dim3(32, 16), blk, 0, stream>>>(qkvd, lp, 32, 256);
        softmax48<<<dim3(32), blk, 0, stream>>>(lp, inv, abf, 32, 64);
        gemm48<float, bf16><<<dim3(8, 128, 4), blk, 0, stream>>>(
            x, x, 384, 384, 384, 0, 384, 384, 0, 384,
            w_bs_pw, 1, 0, 48, 0, y1, 1, 0, 48, 384, 0);
        dw3x3v<<<dim3(8, 384, 4), blk, 0, stream>>>(
            y1, w_bs_dw, yg, 0, 0, 384, 0, 384, 0, 0, 1);
        av_mfma<<<dim3(128, 32), blk, 0, stream>>>(abf, qkvd, qkvd, 0, 144);
        gemm48<bf16, float><<<dim3(8, 128, 4), blk, 0, stream>>>(
            qkvd, yg, 384, 768, 48, 576, 144, 384, 0, 384,
            w_proj, 1, 0, 48, 0, out, 1, 0, 48, 384, 0);
    } else {
        // ---------- ULTRA: fully per-head (~139.6 MB) ----------
        bf16* qph   = (bf16*)ws;
        bf16* qkvdh = (bf16*)(ws + SZH);
        bf16* yg    = (bf16*)(ws + 2 * SZH);
        bf16* attn  = (bf16*)(ws + 2 * SZH + SZY);
        float* lp   = (float*)(ws + 2 * SZH + 2 * SZY);
        bf16* abf   = (bf16*)(ws + 2 * SZH + 2 * SZY + 1179648ull);
        float* inv  = (float*)(ws + 2 * SZH + 2 * SZY + 1179648ull + 24576ull);

        gemm48<float, bf16><<<dim3(8, 128, 4), blk, 0, stream>>>(
            x, x, 384, 384, 384, 0, 384, 384, 0, 384,
            w_bs_pw, 1, 0, 48, 0, y1, 1, 0, 48, 384, 0);
        dw3x3v<<<dim3(8, 384, 4), blk, 0, stream>>>(
            y1, w_bs_dw, yg, 0, 0, 384, 0, 384, 0, 0, 1);
        for (int h = 0; h < 8; ++h) {
            gemm48<float, bf16><<<dim3(3, 128, 4), blk, 0, stream>>>(
                x, x, 384, 384, 384, 0, 384, 384, 0, 384,
                w_qkv, 3, 384, 48, h * 48, qph, 3, 48, 0, 144, 0);
            dw3x3v<<<dim3(8, 144, 4), blk, 0, stream>>>(
                qph, w_dw, qkvdh, 1, h * 48, 144, 0, 144, 0, 0, 0);
            l2norm_v<<<dim3(2 * 4 * 48), blk, 0, stream>>>(qkvdh, inv, 4);
            qk_mfma<<<dim3(4, 8), blk, 0, stream>>>(qkvdh, lp, 4, 512);
            softmax48<<<dim3(4), blk, 0, stream>>>(lp, inv, abf, 4, 32);
            av_mfma<<<dim3(128, 4), blk, 0, stream>>>(abf, qkvdh, attn, h * 48, 384);
        }
        gemm48<bf16, float><<<dim3(8, 128, 4), blk, 0, stream>>>(
            attn, yg, 384, 768, 384, 0, 384, 384, 0, 384,
            w_proj, 1, 0, 48, 0, out, 1, 0, 48, 384, 0);
    }
}

// Round 5
// 743.912 us; speedup vs baseline: 1.3678x; 1.3678x over previous
//
#include <hip/hip_runtime.h>
#include <hip/hip_bf16.h>
#include <math.h>

typedef __hip_bfloat16 bf16;
typedef short bf16x8 __attribute__((ext_vector_type(8)));
typedef float f32x4 __attribute__((ext_vector_type(4)));

#define NPIX 16384  // 128*128 spatial per channel

static __device__ __forceinline__ float ldv(float v) { return v; }
static __device__ __forceinline__ float ldv(bf16 v) { return __bfloat162float(v); }
static __device__ __forceinline__ float lds16(short s) {
    union { short s_; bf16 h; } u; u.s_ = s; return __bfloat162float(u.h);
}
template <typename T> static __device__ __forceinline__ T stv(float v);
template <> __device__ __forceinline__ float stv<float>(float v) { return v; }
template <> __device__ __forceinline__ bf16 stv<bf16>(float v) { return __float2bfloat16(v); }
static __device__ __forceinline__ short stv16(float v) {
    union { short s_; bf16 h; } u; u.h = __float2bfloat16(v); return u.s_;
}

static __device__ __forceinline__ unsigned pack2f(float a, float b) {
    union { bf16 h; unsigned short u; } ua, ub;
    ua.h = __float2bfloat16(a); ub.h = __float2bfloat16(b);
    return (unsigned)ua.u | ((unsigned)ub.u << 16);
}
static __device__ __forceinline__ unsigned packbb(unsigned short lo, unsigned short hi) {
    return (unsigned)lo | ((unsigned)hi << 16);
}

template <typename SrcT>
static __device__ __forceinline__ const SrcT* maprow(const SrcT* A, const SrcT* B, int k,
    int Ksplit, int agrp, int ags, int abss, int bgrp, int bgs, int bbs, int b)
{
    if (k < Ksplit) return A + (size_t)((k / agrp) * ags + b * abss + (k % agrp)) * NPIX;
    k -= Ksplit;
    return B + (size_t)((k / bgrp) * bgs + b * bbs + (k % bgrp)) * NPIX;
}

// ---------------------------------------------------------------------------
// Pack f32 weights -> bf16, flat. grid: n/2048, block 256.
// ---------------------------------------------------------------------------
__global__ __launch_bounds__(256) void packw(const float* __restrict__ s,
                                             bf16* __restrict__ d, int n)
{
    int i = (blockIdx.x * 256 + threadIdx.x) * 8;
    if (i + 8 > n) return;
    float4 v0 = *(const float4*)(s + i);
    float4 v1 = *(const float4*)(s + i + 4);
    uint4 u;
    u.x = pack2f(v0.x, v0.y); u.y = pack2f(v0.z, v0.w);
    u.z = pack2f(v1.x, v1.y); u.w = pack2f(v1.z, v1.w);
    *(uint4*)(void*)(d + i) = u;
}

// ---------------------------------------------------------------------------
// Transpose x [b][384][16384] f32 -> xT [b][16384][384] bf16.
// Tile 64 px x 384 ch via LDS with 16B-block XOR swizzle. grid: (256, 4)
// ---------------------------------------------------------------------------
__global__ __launch_bounds__(256) void xpose(const float* __restrict__ x,
                                             bf16* __restrict__ xT)
{
    __shared__ short Ls[64 * 384];
    const int t = threadIdx.x;
    const int px0 = blockIdx.x * 64;
    const int b = blockIdx.y;
    const float* xb = x + (size_t)b * 384 * NPIX;

#pragma unroll 4
    for (int i = 0; i < 24; ++i) {
        int e = i * 256 + t;
        int ch = e >> 4, seg = e & 15;
        float4 v = *(const float4*)(xb + (size_t)ch * NPIX + px0 + seg * 4);
        const float* vp = (const float*)&v;
#pragma unroll
        for (int j = 0; j < 4; ++j) {
            int px = seg * 4 + j;
            int B = (ch >> 3) ^ ((px >> 2) & 7);
            Ls[px * 384 + B * 8 + (ch & 7)] = stv16(vp[j]);
        }
    }
    __syncthreads();

    const int lpx = t >> 2;
    const int m = (lpx >> 2) & 7;
    bf16* ob = xT + ((size_t)b * NPIX + px0 + lpx) * 384;
#pragma unroll
    for (int j = 0; j < 12; ++j) {
        int B = (t & 3) + j * 4;
        bf16x8 blk = *(const bf16x8*)&Ls[lpx * 384 + (B ^ m) * 8];
        *(bf16x8*)(void*)(ob + B * 8) = blk;
    }
}

// ---------------------------------------------------------------------------
// Transpose bf16 ch-major [b][384][16K] -> px-major pxT[b][16K][768] upper half
// (ch offset +384). Same LDS swizzle as xpose. grid: (256, 4)
// ---------------------------------------------------------------------------
__global__ __launch_bounds__(256) void xposeB(const bf16* __restrict__ src,
                                              bf16* __restrict__ dst)
{
    __shared__ short Ls[64 * 384];
    const int t = threadIdx.x;
    const int px0 = blockIdx.x * 64;
    const int b = blockIdx.y;
    const bf16* sb = src + (size_t)b * 384 * NPIX;

#pragma unroll 4
    for (int i = 0; i < 12; ++i) {
        int e = i * 256 + t;               // 3072 x 16B loads
        int ch = e >> 3, seg = e & 7;
        bf16x8 v = *(const bf16x8*)(const void*)(sb + (size_t)ch * NPIX + px0 + seg * 8);
#pragma unroll
        for (int j = 0; j < 8; ++j) {
            int px = seg * 8 + j;
            int B = (ch >> 3) ^ ((px >> 2) & 7);
            Ls[px * 384 + B * 8 + (ch & 7)] = v[j];
        }
    }
    __syncthreads();

    const int lpx = t >> 2;
    const int m = (lpx >> 2) & 7;
    bf16* ob = dst + ((size_t)b * NPIX + px0 + lpx) * 768 + 384;
#pragma unroll
    for (int j = 0; j < 12; ++j) {
        int B = (t & 3) + j * 4;
        bf16x8 blk = *(const bf16x8*)&Ls[lpx * 384 + (B ^ m) * 8];
        *(bf16x8*)(void*)(ob + B * 8) = blk;
    }
}

// ---------------------------------------------------------------------------
// gemm3: m97-style LDS double-buffered MFMA GEMM, B already px-major (row
// copy staging, no transpose, no cvt). BMxBN = BMx128, BK=32, 4 waves each
// owning all M-tiles x 32 px. One barrier/step; global loads issued before
// the MFMA cluster, ds_write after (vmcnt wait lands post-MFMA).
//   A row for tile elem r:  bm*wrowMul + (r/G)*wsA + r%G   (packed bf16, stride K)
//   B row:                  (b*NPIX + px0 + px) * K
//   out row:                bm*osA + b*obS + r              (contiguous BM rows)
// grid: 1D nwg, XCD-chunked: w = (gid&7)*(nwg/8) + gid>>3; w = grp*bmCount+bm,
//       grp = pxt*4+b  -> all bm sharing a px-tile land on one XCD.
// ---------------------------------------------------------------------------
template <int BM, int K, typename OutT>
__global__ __launch_bounds__(256) void gemm3(
    const bf16* __restrict__ wp, int G, int wsA, int wrowMul,
    const bf16* __restrict__ bsrc,
    OutT* __restrict__ out, int osA, int obS,
    int bmCount, int nwg)
{
    constexpr int MT = BM / 16;       // m-tiles
    constexpr int S  = K / 32;        // K-steps
    constexpr int ACH = BM * 4;       // 16B A-chunks per step
    __shared__ __align__(16) short As[2][BM * 40];
    __shared__ __align__(16) short Bs[2][128 * 40];

    const int t = threadIdx.x;
    const int gid = blockIdx.x;
    const int w = (gid & 7) * (nwg >> 3) + (gid >> 3);
    const int bm = w % bmCount, grp = w / bmCount;
    const int b = grp & 3, px0 = (grp >> 2) * 128;

    const int l = t & 63, wvid = t >> 6, l15 = l & 15, q = l >> 4;
    const int wr0 = bm * wrowMul;
    const size_t bRow0 = (size_t)b * NPIX + px0;

    // per-thread staging chunk pointers (rows fixed; only kk advances)
    const int e0 = t,        r0 = e0 >> 2, c0 = e0 & 3;
    const int e1 = t + 256,  r1 = e1 >> 2, c1 = e1 & 3;
    const bf16* apt0 = wp + (size_t)(wr0 + (r0 / G) * wsA + (r0 % G)) * K + c0 * 8;
    const bf16* apt1 = wp + (size_t)(wr0 + (r1 / G) * wsA + (r1 % G)) * K + c1 * 8;
    const int sA0 = r0 * 40 + c0 * 8, sA1 = r1 * 40 + c1 * 8;
    const bf16* apt2 = apt0; int sA2 = sA0; bool has2 = false;
    if constexpr (ACH > 512) {
        if (t < ACH - 512) {
            int e2 = t + 512, r2 = e2 >> 2, c2 = e2 & 3;
            apt2 = wp + (size_t)(wr0 + (r2 / G) * wsA + (r2 % G)) * K + c2 * 8;
            sA2 = r2 * 40 + c2 * 8;
            has2 = true;
        }
    }
    const bf16* bpt0 = bsrc + (bRow0 + r0) * K + c0 * 8;
    const bf16* bpt1 = bsrc + (bRow0 + r1) * K + c1 * 8;

    f32x4 acc[MT][2];
#pragma unroll
    for (int mt = 0; mt < MT; ++mt)
#pragma unroll
        for (int nt = 0; nt < 2; ++nt) acc[mt][nt] = (f32x4){0.f, 0.f, 0.f, 0.f};

    bf16x8 aR0, aR1, aR2, bR0, bR1;

    auto GLOADS = [&](int kk) {
        aR0 = *(const bf16x8*)(const void*)(apt0 + kk);
        aR1 = *(const bf16x8*)(const void*)(apt1 + kk);
        if constexpr (ACH > 512) { if (has2) aR2 = *(const bf16x8*)(const void*)(apt2 + kk); }
        bR0 = *(const bf16x8*)(const void*)(bpt0 + kk);
        bR1 = *(const bf16x8*)(const void*)(bpt1 + kk);
    };
    auto SSTORES = [&](int buf) {
        *(bf16x8*)&As[buf][sA0] = aR0;
        *(bf16x8*)&As[buf][sA1] = aR1;
        if constexpr (ACH > 512) { if (has2) *(bf16x8*)&As[buf][sA2] = aR2; }
        *(bf16x8*)&Bs[buf][sA0] = bR0;   // B chunk indices coincide with A's e0/e1
        *(bf16x8*)&Bs[buf][sA1] = bR1;
    };

    GLOADS(0);
    SSTORES(0);
    __syncthreads();

#pragma unroll
    for (int s = 0; s < S; ++s) {
        const int cur = s & 1;
        if (s + 1 < S) GLOADS((s + 1) * 32);
        bf16x8 af[MT], bfv[2];
#pragma unroll
        for (int mt = 0; mt < MT; ++mt)
            af[mt] = *(const bf16x8*)&As[cur][(mt * 16 + l15) * 40 + q * 8];
#pragma unroll
        for (int nt = 0; nt < 2; ++nt)
            bfv[nt] = *(const bf16x8*)&Bs[cur][(wvid * 32 + nt * 16 + l15) * 40 + q * 8];
#pragma unroll
        for (int mt = 0; mt < MT; ++mt)
#pragma unroll
            for (int nt = 0; nt < 2; ++nt)
                acc[mt][nt] = __builtin_amdgcn_mfma_f32_16x16x32_bf16(
                    af[mt], bfv[nt], acc[mt][nt], 0, 0, 0);
        if (s + 1 < S) SSTORES(1 - cur);
        __syncthreads();
    }

    const int obase = bm * osA + b * obS;
#pragma unroll
    for (int mt = 0; mt < MT; ++mt)
#pragma unroll
        for (int nt = 0; nt < 2; ++nt)
#pragma unroll
            for (int r = 0; r < 4; ++r) {
                int row = obase + mt * 16 + q * 4 + r;
                int col = px0 + wvid * 32 + nt * 16 + l15;
                out[(size_t)row * NPIX + col] = stv<OutT>(acc[mt][nt][r]);
            }
}

// ---------------------------------------------------------------------------
// Pipelined MFMA pointwise GEMM (kept for LITE/ULTRA fallback paths)
// ---------------------------------------------------------------------------
template <typename SrcT, typename OutT>
__global__ __launch_bounds__(256) void gemm48(
    const SrcT* __restrict__ srcA, const SrcT* __restrict__ srcB, int Ksplit, int K,
    int agrp, int ags, int abss, int bgrp, int bgs, int bbs,
    const float* __restrict__ w, int wMod, int wsA, int wsB, int wrow0,
    OutT* __restrict__ out, int oMod, int osA, int osB, int obS, int orow0)
{
    __shared__ __align__(16) short As[2][48 * 40];
    __shared__ __align__(16) short Bs[2][128 * 40];

    const int t  = threadIdx.x;
    const int bm = blockIdx.x;
    const int p0 = blockIdx.y * 128;
    const int b  = blockIdx.z;

    const int l = t & 63, wvid = t >> 6, l15 = l & 15, q = l >> 4;
    const int c4 = t >> 4, rp = t & 15;

    const int wbase = wrow0 + (bm % wMod) * wsA + (bm / wMod) * wsB;

    f32x4 acc[3][2];
#pragma unroll
    for (int mt = 0; mt < 3; ++mt)
#pragma unroll
        for (int nt = 0; nt < 2; ++nt) acc[mt][nt] = (f32x4){0.f, 0.f, 0.f, 0.f};

    float aw[6];
    float fb[16];
    bf16x8 hA, hB;

    auto LOADA = [&](int k0) {
#pragma unroll
        for (int i = 0; i < 3; ++i) {
            int idx = t + i * 256, row = idx >> 4, kq = idx & 15;
            float2 v = *(const float2*)(w + (size_t)(wbase + row) * K + k0 + kq * 2);
            aw[2 * i] = v.x; aw[2 * i + 1] = v.y;
        }
    };
    auto STOREA = [&](int buf) {
#pragma unroll
        for (int i = 0; i < 3; ++i) {
            int idx = t + i * 256, row = idx >> 4, kq = idx & 15;
            *(unsigned*)&As[buf][row * 40 + kq * 2] = pack2f(aw[2 * i], aw[2 * i + 1]);
        }
    };
    auto LOADB = [&](int k0) {
        const SrcT* r0 = maprow(srcA, srcB, k0 + 2 * rp,     Ksplit, agrp, ags, abss, bgrp, bgs, bbs, b) + p0 + c4 * 8;
        const SrcT* r1 = maprow(srcA, srcB, k0 + 2 * rp + 1, Ksplit, agrp, ags, abss, bgrp, bgs, bbs, b) + p0 + c4 * 8;
        if constexpr (sizeof(SrcT) == 4) {
            float4 a0 = *(const float4*)r0, a1 = *(const float4*)(r0 + 4);
            float4 b0 = *(const float4*)r1, b1 = *(const float4*)(r1 + 4);
            fb[0] = a0.x; fb[1] = a0.y; fb[2] = a0.z; fb[3] = a0.w;
            fb[4] = a1.x; fb[5] = a1.y; fb[6] = a1.z; fb[7] = a1.w;
            fb[8] = b0.x; fb[9] = b0.y; fb[10] = b0.z; fb[11] = b0.w;
            fb[12] = b1.x; fb[13] = b1.y; fb[14] = b1.z; fb[15] = b1.w;
        } else {
            hA = *(const bf16x8*)(const void*)r0;
            hB = *(const bf16x8*)(const void*)r1;
        }
    };
    auto STOREB = [&](int buf) {
#pragma unroll
        for (int j = 0; j < 8; ++j) {
            unsigned d;
            if constexpr (sizeof(SrcT) == 4) d = pack2f(fb[j], fb[8 + j]);
            else d = packbb((unsigned short)hA[j], (unsigned short)hB[j]);
            *(unsigned*)&Bs[buf][(c4 * 8 + j) * 40 + rp * 2] = d;
        }
    };

    LOADA(0); LOADB(0);
    STOREA(0); STOREB(0);
    const int S = K / 32;
    for (int s = 0; s < S; ++s) {
        const int cur = s & 1;
        __syncthreads();
        if (s + 1 < S) { LOADA((s + 1) * 32); LOADB((s + 1) * 32); }
        bf16x8 af[3], bfr[2];
#pragma unroll
        for (int mt = 0; mt < 3; ++mt)
            af[mt] = *(const bf16x8*)&As[cur][(mt * 16 + l15) * 40 + q * 8];
#pragma unroll
        for (int nt = 0; nt < 2; ++nt)
            bfr[nt] = *(const bf16x8*)&Bs[cur][(wvid * 32 + nt * 16 + l15) * 40 + q * 8];
#pragma unroll
        for (int mt = 0; mt < 3; ++mt)
#pragma unroll
            for (int nt = 0; nt < 2; ++nt)
                acc[mt][nt] = __builtin_amdgcn_mfma_f32_16x16x32_bf16(
                    af[mt], bfr[nt], acc[mt][nt], 0, 0, 0);
        if (s + 1 < S) { STOREA(1 - cur); STOREB(1 - cur); }
    }

    const int obase = orow0 + (bm % oMod) * osA + (bm / oMod) * osB + b * obS;
#pragma unroll
    for (int mt = 0; mt < 3; ++mt)
#pragma unroll
        for (int nt = 0; nt < 2; ++nt)
#pragma unroll
            for (int r = 0; r < 4; ++r) {
                int row = obase + mt * 16 + q * 4 + r;
                int col = p0 + wvid * 32 + nt * 16 + l15;
                out[(size_t)row * NPIX + col] = stv<OutT>(acc[mt][nt][r]);
            }
}

// ---------------------------------------------------------------------------
// Vectorized depthwise 3x3 (+optional exact GELU). 8 px/thread, b128 loads.
// ---------------------------------------------------------------------------
__global__ __launch_bounds__(256) void dw3x3v(
    const bf16* __restrict__ in, const float* __restrict__ w, bf16* __restrict__ out,
    int isQkv, int whofs, int inB, int ig, int outB, int og, int obase, int applyGelu)
{
    const int t = threadIdx.x;
    const int g = blockIdx.x * 256 + t;
    const int c = blockIdx.y;
    const int b = blockIdx.z;
    const int y = g >> 4;
    const int x0 = (g & 15) * 8;

    int inRow, wch, outRow;
    if (isQkv) {
        int h = c / 144, r = c - h * 144;
        inRow  = h * ig + b * inB + r;
        wch    = (r / 48) * 384 + h * 48 + whofs + (r % 48);
        outRow = h * og + b * outB + r + obase;
    } else {
        inRow = b * inB + c; wch = c; outRow = b * outB + c;
    }

    const bf16* ib = in + (size_t)inRow * NPIX;
    float wv[9];
#pragma unroll
    for (int i = 0; i < 9; ++i) wv[i] = w[wch * 9 + i];

    float vv[3][10];
#pragma unroll
    for (int dy = 0; dy < 3; ++dy) {
        int yy = y + dy - 1;
        if (yy < 0 || yy > 127) {
#pragma unroll
            for (int j = 0; j < 10; ++j) vv[dy][j] = 0.f;
        } else {
            const bf16* rb = ib + yy * 128;
            bf16x8 m = *(const bf16x8*)(const void*)(rb + x0);
#pragma unroll
            for (int j = 0; j < 8; ++j) vv[dy][j + 1] = lds16(m[j]);
            vv[dy][0] = (x0 > 0)   ? ldv(rb[x0 - 1]) : 0.f;
            vv[dy][9] = (x0 < 120) ? ldv(rb[x0 + 8]) : 0.f;
        }
    }
    bf16x8 res;
#pragma unroll
    for (int j = 0; j < 8; ++j) {
        float a = 0.f;
#pragma unroll
        for (int dy = 0; dy < 3; ++dy)
#pragma unroll
            for (int dx = 0; dx < 3; ++dx)
                a += wv[dy * 3 + dx] * vv[dy][j + dx];
        if (applyGelu) a = 0.5f * a * (1.0f + erff(a * 0.70710678118654752f));
        res[j] = stv16(a);
    }
    *(bf16x8*)(void*)(out + (size_t)outRow * NPIX + y * 128 + x0) = res;
}

// ---------------------------------------------------------------------------
// inv-L2-norm, vectorized. grid: 2*NBH*48 blocks over qkvd [bh][144][p].
// ---------------------------------------------------------------------------
__global__ __launch_bounds__(256) void l2norm_v(const bf16* __restrict__ qkvd,
                                                float* __restrict__ inv, int NBH)
{
    const int id = blockIdx.x;
    const int which = id / (NBH * 48);
    const int rem = id - which * NBH * 48;
    const int bh = rem / 48, c = rem - bh * 48;
    const bf16* base = qkvd + (size_t)(bh * 144 + which * 48 + c) * NPIX;

    float s = 0.f;
#pragma unroll
    for (int it = 0; it < 8; ++it) {
        bf16x8 v = *(const bf16x8*)(const void*)(base + ((size_t)threadIdx.x + it * 256) * 8);
#pragma unroll
        for (int j = 0; j < 8; ++j) { float f = lds16(v[j]); s += f * f; }
    }
#pragma unroll
    for (int off = 32; off; off >>= 1) s += __shfl_down(s, off, 64);
    __shared__ float partial[4];
    if ((threadIdx.x & 63) == 0) partial[threadIdx.x >> 6] = s;
    __syncthreads();
    if (threadIdx.x == 0) {
        float tt = partial[0] + partial[1] + partial[2] + partial[3];
        inv[(which * NBH + bh) * 48 + c] = 1.0f / fmaxf(sqrtf(tt), 1e-12f);
    }
}

// ---------------------------------------------------------------------------
// QK^T logits partials via MFMA, direct-from-global fragments.
// ---------------------------------------------------------------------------
__global__ __launch_bounds__(256) void qk_mfma(const bf16* __restrict__ qkvd,
                                               float* __restrict__ lp, int NBH, int pxs)
{
    const int bh = blockIdx.x;
    const int wvid = threadIdx.x >> 6;
    const int slice = blockIdx.y * 4 + wvid;
    const int l = threadIdx.x & 63, l15 = l & 15, q = l >> 4;

    const bf16* qb = qkvd + (size_t)(bh * 144) * NPIX;
    const bf16* kb = qb + (size_t)48 * NPIX;

    f32x4 acc[3][3];
#pragma unroll
    for (int mt = 0; mt < 3; ++mt)
#pragma unroll
        for (int nt = 0; nt < 3; ++nt) acc[mt][nt] = (f32x4){0.f, 0.f, 0.f, 0.f};

    const int pbeg = slice * pxs;
    for (int kk = 0; kk < pxs; kk += 32) {
        const int pc = pbeg + kk + q * 8;
        bf16x8 af[3], bfv[3];
#pragma unroll
        for (int mt = 0; mt < 3; ++mt)
            af[mt] = *(const bf16x8*)(const void*)(qb + (size_t)(mt * 16 + l15) * NPIX + pc);
#pragma unroll
        for (int nt = 0; nt < 3; ++nt)
            bfv[nt] = *(const bf16x8*)(const void*)(kb + (size_t)(nt * 16 + l15) * NPIX + pc);
#pragma unroll
        for (int mt = 0; mt < 3; ++mt)
#pragma unroll
            for (int nt = 0; nt < 3; ++nt)
                acc[mt][nt] = __builtin_amdgcn_mfma_f32_16x16x32_bf16(
                    af[mt], bfv[nt], acc[mt][nt], 0, 0, 0);
    }
    float* o = lp + ((size_t)slice * NBH + bh) * 2304;
#pragma unroll
    for (int mt = 0; mt < 3; ++mt)
#pragma unroll
        for (int nt = 0; nt < 3; ++nt)
#pragma unroll
            for (int r = 0; r < 4; ++r)
                o[(mt * 16 + q * 4 + r) * 48 + nt * 16 + l15] = acc[mt][nt][r];
}

// ---------------------------------------------------------------------------
// Sum NSL slice-partials, apply scale*invq*invk, row-softmax, emit bf16.
// ---------------------------------------------------------------------------
__global__ __launch_bounds__(256) void softmax48(const float* __restrict__ lp,
                                                 const float* __restrict__ inv,
                                                 bf16* __restrict__ a_bf, int NBH, int NSL)
{
    const int bh = blockIdx.x, t = threadIdx.x;
    __shared__ float L[2304];
    for (int e = t; e < 2304; e += 256) {
        float s = 0.f;
        for (int sl = 0; sl < NSL; ++sl) s += lp[((size_t)sl * NBH + bh) * 2304 + e];
        int i = e / 48, j = e - i * 48;
        L[e] = s * 0.14433756729740643f * inv[bh * 48 + i] * inv[(NBH + bh) * 48 + j];
    }
    __syncthreads();
    if (t < 48) {
        float m = -1e30f;
#pragma unroll
        for (int j = 0; j < 48; ++j) m = fmaxf(m, L[t * 48 + j]);
        float e_[48]; float ssum = 0.f;
#pragma unroll
        for (int j = 0; j < 48; ++j) { e_[j] = expf(L[t * 48 + j] - m); ssum += e_[j]; }
        float r = 1.f / ssum;
        bf16* ab = a_bf + (size_t)bh * 3072 + t * 64;
#pragma unroll
        for (int j = 0; j < 48; ++j) ab[j] = stv<bf16>(e_[j] * r);
#pragma unroll
        for (int j = 48; j < 64; ++j) ab[j] = stv<bf16>(0.f);
    }
}

// ---------------------------------------------------------------------------
// AV via MFMA, ch-major output (LITE/ULTRA paths).
// ---------------------------------------------------------------------------
__global__ __launch_bounds__(256) void av_mfma(const bf16* __restrict__ a_bf,
                                               const bf16* __restrict__ qkvd,
                                               bf16* __restrict__ out, int obase, int oS)
{
    __shared__ __align__(16) short Bs[128 * 72];
    const int t = threadIdx.x;
    const int px0 = blockIdx.x * 128;
    const int bh = blockIdx.y;
    const int l = t & 63, wvid = t >> 6, l15 = l & 15, q = l >> 4;
    const int c4 = t >> 4, rp = t & 15;

    const bf16* ab = a_bf + (size_t)bh * 3072;
    bf16x8 af[3][2];
#pragma unroll
    for (int mt = 0; mt < 3; ++mt)
#pragma unroll
        for (int kq = 0; kq < 2; ++kq)
            af[mt][kq] = *(const bf16x8*)(const void*)(ab + (mt * 16 + l15) * 64 + kq * 32 + q * 8);

    const bf16* vb = qkvd + (size_t)(bh * 144 + 96) * NPIX;
    bf16x8 vr[4];
#pragma unroll
    for (int jj = 0; jj < 4; ++jj) {
        int j = rp * 4 + jj; int jc = j < 48 ? j : 47;
        vr[jj] = *(const bf16x8*)(const void*)(vb + (size_t)jc * NPIX + px0 + c4 * 8);
    }
#pragma unroll
    for (int j = 0; j < 8; ++j) {
        *(unsigned*)&Bs[(c4 * 8 + j) * 72 + rp * 4]     = packbb((unsigned short)vr[0][j], (unsigned short)vr[1][j]);
        *(unsigned*)&Bs[(c4 * 8 + j) * 72 + rp * 4 + 2] = packbb((unsigned short)vr[2][j], (unsigned short)vr[3][j]);
    }
    __syncthreads();

    f32x4 acc[3][2];
#pragma unroll
    for (int mt = 0; mt < 3; ++mt)
#pragma unroll
        for (int nt = 0; nt < 2; ++nt) acc[mt][nt] = (f32x4){0.f, 0.f, 0.f, 0.f};

    bf16x8 bfv[2][2];
#pragma unroll
    for (int nt = 0; nt < 2; ++nt)
#pragma unroll
        for (int kq = 0; kq < 2; ++kq)
            bfv[nt][kq] = *(const bf16x8*)&Bs[(wvid * 32 + nt * 16 + l15) * 72 + kq * 32 + q * 8];
#pragma unroll
    for (int kq = 0; kq < 2; ++kq)
#pragma unroll
        for (int mt = 0; mt < 3; ++mt)
#pragma unroll
            for (int nt = 0; nt < 2; ++nt)
                acc[mt][nt] = __builtin_amdgcn_mfma_f32_16x16x32_bf16(
                    af[mt][kq], bfv[nt][kq], acc[mt][nt], 0, 0, 0);
#pragma unroll
    for (int mt = 0; mt < 3; ++mt)
#pragma unroll
        for (int nt = 0; nt < 2; ++nt)
#pragma unroll
            for (int r = 0; r < 4; ++r) {
                int row = obase + bh * oS + mt * 16 + q * 4 + r;
                int col = px0 + wvid * 32 + nt * 16 + l15;
                out[(size_t)row * NPIX + col] = stv<bf16>(acc[mt][nt][r]);
            }
}

// ---------------------------------------------------------------------------
// AV via MFMA, px-major output into pxT[b][16K][768] lower half (ch h*48+c).
// grid: (128, NBH=32)
// ---------------------------------------------------------------------------
__global__ __launch_bounds__(256) void av_mfma2(const bf16* __restrict__ a_bf,
                                                const bf16* __restrict__ qkvd,
                                                bf16* __restrict__ pxT)
{
    __shared__ __align__(16) short Bs[128 * 72];
    const int t = threadIdx.x;
    const int px0 = blockIdx.x * 128;
    const int bh = blockIdx.y;
    const int l = t & 63, wvid = t >> 6, l15 = l & 15, q = l >> 4;
    const int c4 = t >> 4, rp = t & 15;

    const bf16* ab = a_bf + (size_t)bh * 3072;
    bf16x8 af[3][2];
#pragma unroll
    for (int mt = 0; mt < 3; ++mt)
#pragma unroll
        for (int kq = 0; kq < 2; ++kq)
            af[mt][kq] = *(const bf16x8*)(const void*)(ab + (mt * 16 + l15) * 64 + kq * 32 + q * 8);

    const bf16* vb = qkvd + (size_t)(bh * 144 + 96) * NPIX;
    bf16x8 vr[4];
#pragma unroll
    for (int jj = 0; jj < 4; ++jj) {
        int j = rp * 4 + jj; int jc = j < 48 ? j : 47;
        vr[jj] = *(const bf16x8*)(const void*)(vb + (size_t)jc * NPIX + px0 + c4 * 8);
    }
#pragma unroll
    for (int j = 0; j < 8; ++j) {
        *(unsigned*)&Bs[(c4 * 8 + j) * 72 + rp * 4]     = packbb((unsigned short)vr[0][j], (unsigned short)vr[1][j]);
        *(unsigned*)&Bs[(c4 * 8 + j) * 72 + rp * 4 + 2] = packbb((unsigned short)vr[2][j], (unsigned short)vr[3][j]);
    }
    __syncthreads();

    f32x4 acc[3][2];
#pragma unroll
    for (int mt = 0; mt < 3; ++mt)
#pragma unroll
        for (int nt = 0; nt < 2; ++nt) acc[mt][nt] = (f32x4){0.f, 0.f, 0.f, 0.f};

    bf16x8 bfv[2][2];
#pragma unroll
    for (int nt = 0; nt < 2; ++nt)
#pragma unroll
        for (int kq = 0; kq < 2; ++kq)
            bfv[nt][kq] = *(const bf16x8*)&Bs[(wvid * 32 + nt * 16 + l15) * 72 + kq * 32 + q * 8];
#pragma unroll
    for (int kq = 0; kq < 2; ++kq)
#pragma unroll
        for (int mt = 0; mt < 3; ++mt)
#pragma unroll
            for (int nt = 0; nt < 2; ++nt)
                acc[mt][nt] = __builtin_amdgcn_mfma_f32_16x16x32_bf16(
                    af[mt][kq], bfv[nt][kq], acc[mt][nt], 0, 0, 0);

    // transpose acc -> Bs[pxl][48ch] bf16, then coalesced px-major stores
    __syncthreads();
#pragma unroll
    for (int mt = 0; mt < 3; ++mt)
#pragma unroll
        for (int nt = 0; nt < 2; ++nt) {
            int pxl = wvid * 32 + nt * 16 + l15;
#pragma unroll
            for (int r = 0; r < 2; ++r)
                *(unsigned*)&Bs[pxl * 48 + mt * 16 + q * 4 + r * 2] =
                    pack2f(acc[mt][nt][2 * r], acc[mt][nt][2 * r + 1]);
        }
    __syncthreads();

    const int h = bh >> 2, bb = bh & 3;
    const int pxl = t >> 1, half = t & 1;
    bf16* ob = pxT + ((size_t)bb * NPIX + px0 + pxl) * 768 + h * 48 + half * 24;
#pragma unroll
    for (int j = 0; j < 3; ++j)
        *(bf16x8*)(void*)(ob + j * 8) = *(const bf16x8*)&Bs[pxl * 48 + half * 24 + j * 8];
}

// ---------------------------------------------------------------------------
extern "C" void kernel_launch(void* const* d_in, const int* in_sizes, int n_in,
                              void* d_out, int out_size, void* d_ws, size_t ws_size,
                              hipStream_t stream) {
    const float* x       = (const float*)d_in[0];
    const float* w_qkv   = (const float*)d_in[1];
    const float* w_dw    = (const float*)d_in[2];
    const float* w_proj  = (const float*)d_in[3];
    const float* w_bs_pw = (const float*)d_in[4];
    const float* w_bs_dw = (const float*)d_in[5];
    float* out = (float*)d_out;
    bf16* y1 = (bf16*)d_out;  // bs_pw bf16 output lives in d_out space until proj

    const size_t SZQ = 150994944ull;  // 8h*4b*144*16384*2
    const size_t SZH = 18874368ull;   // 4b*144*16384*2
    const size_t SZY = 50331648ull;   // 4b*384*16384*2
    const size_t SZPXT = 100663296ull; // 4b*16384*768*2
    char* ws = (char*)d_ws;
    dim3 blk(256);

    if (ws_size >= 371404800ull) {
        // ---------- FULL: all heads batched ----------
        bf16* qkvp = (bf16*)ws;
        bf16* pxT  = (bf16*)ws;
        bf16* wprojp = (bf16*)(ws + SZPXT);
        bf16* qkvd = (bf16*)(ws + SZQ);
        bf16* xT   = (bf16*)(ws + 2 * SZQ);
        bf16* yg   = xT;
        float* lp  = (float*)(ws + 2 * SZQ + SZY);
        bf16* wqkvp = (bf16*)lp;
        bf16* wbsp  = (bf16*)((char*)lp + 884736ull);
        bf16* abf  = (bf16*)(ws + 2 * SZQ + SZY + 18874368ull);
        float* inv = (float*)(ws + 2 * SZQ + SZY + 18874368ull + 196608ull);

        packw<<<dim3(216), blk, 0, stream>>>(w_qkv, wqkvp, 442368);
        packw<<<dim3(72), blk, 0, stream>>>(w_bs_pw, wbsp, 147456);
        xpose<<<dim3(256, 4), blk, 0, stream>>>(x, xT);
        // qkv: BM=144 (one head: q+k+v 48-row groups, wsA=384), out qkvp[h][b][144]
        gemm3<144, 384, bf16><<<dim3(4096), blk, 0, stream>>>(
            wqkvp, 48, 384, 48, xT, qkvp, 576, 144, 8, 4096);
        dw3x3v<<<dim3(8, 1152, 4), blk, 0, stream>>>(
            qkvp, w_dw, qkvd, 1, 0, 144, 576, 144, 576, 0, 0);
        packw<<<dim3(144), blk, 0, stream>>>(w_proj, wprojp, 294912);  // qkvp dead
        // bs_pw: BM=128 x 3 tiles over 384 rows, out y1[b][384]
        gemm3<128, 384, bf16><<<dim3(1536), blk, 0, stream>>>(
            wbsp, 128, 0, 128, xT, y1, 128, 384, 3, 1536);
        dw3x3v<<<dim3(8, 384, 4), blk, 0, stream>>>(
            y1, w_bs_dw, yg, 0, 0, 384, 0, 384, 0, 0, 1);          // xT dead, yg over it
        xposeB<<<dim3(256, 4), blk, 0, stream>>>(yg, pxT);         // yg -> pxT[.., 384:768]
        l2norm_v<<<dim3(2 * 32 * 48), blk, 0, stream>>>(qkvd, inv, 32);
        qk_mfma<<<dim3(32, 16), blk, 0, stream>>>(qkvd, lp, 32, 256);
        softmax48<<<dim3(32), blk, 0, stream>>>(lp, inv, abf, 32, 64);
        av_mfma2<<<dim3(128, 32), blk, 0, stream>>>(abf, qkvd, pxT); // -> pxT[.., 0:384]
        // proj: K=768 from pxT, out f32 [b][384]
        gemm3<128, 768, float><<<dim3(1536), blk, 0, stream>>>(
            wprojp, 128, 0, 128, pxT, out, 128, 384, 3, 1536);
    } else if (ws_size >= 239284224ull) {
        // ---------- LITE: per-head pw+dw, rest batched ----------
        bf16* qkvd = (bf16*)ws;
        bf16* qph  = (bf16*)(ws + SZQ);
        bf16* yg   = (bf16*)(ws + SZQ + SZH);
        float* lp  = (float*)(ws + SZQ + SZH + SZY);
        bf16* abf  = (bf16*)(ws + SZQ + SZH + SZY + 18874368ull);
        float* inv = (float*)(ws + SZQ + SZH + SZY + 18874368ull + 196608ull);

        for (int h = 0; h < 8; ++h) {
            gemm48<float, bf16><<<dim3(3, 128, 4), blk, 0, stream>>>(
                x, x, 384, 384, 384, 0, 384, 384, 0, 384,
                w_qkv, 3, 384, 48, h * 48, qph, 3, 48, 0, 144, 0);
            dw3x3v<<<dim3(8, 144, 4), blk, 0, stream>>>(
                qph, w_dw, qkvd, 1, h * 48, 144, 0, 144, 0, h * 576, 0);
        }
        l2norm_v<<<dim3(2 * 32 * 48), blk, 0, stream>>>(qkvd, inv, 32);
        qk_mfma<<<dim3(32, 16), blk, 0, stream>>>(qkvd, lp, 32, 256);
        softmax48<<<dim3(32), blk, 0, stream>>>(lp, inv, abf, 32, 64);
        gemm48<float, bf16><<<dim3(8, 128, 4), blk, 0, stream>>>(
            x, x, 384, 384, 384, 0, 384, 384, 0, 384,
            w_bs_pw, 1, 0, 48, 0, y1, 1, 0, 48, 384, 0);
        dw3x3v<<<dim3(8, 384, 4), blk, 0, stream>>>(
            y1, w_bs_dw, yg, 0, 0, 384, 0, 384, 0, 0, 1);
        av_mfma<<<dim3(128, 32), blk, 0, stream>>>(abf, qkvd, qkvd, 0, 144);
        gemm48<bf16, float><<<dim3(8, 128, 4), blk, 0, stream>>>(
            qkvd, yg, 384, 768, 48, 576, 144, 384, 0, 384,
            w_proj, 1, 0, 48, 0, out, 1, 0, 48, 384, 0);
    } else {
        // ---------- ULTRA: fully per-head (~139.6 MB) ----------
        bf16* qph   = (bf16*)ws;
        bf16* qkvdh = (bf16*)(ws + SZH);
        bf16* yg    = (bf16*)(ws + 2 * SZH);
        bf16* attn  = (bf16*)(ws + 2 * SZH + SZY);
        float* lp   = (float*)(ws + 2 * SZH + 2 * SZY);
        bf16* abf   = (bf16*)(ws + 2 * SZH + 2 * SZY + 1179648ull);
        float* inv  = (float*)(ws + 2 * SZH + 2 * SZY + 1179648ull + 24576ull);

        gemm48<float, bf16><<<dim3(8, 128, 4), blk, 0, stream>>>(
            x, x, 384, 384, 384, 0, 384, 384, 0, 384,
            w_bs_pw, 1, 0, 48, 0, y1, 1, 0, 48, 384, 0);
        dw3x3v<<<dim3(8, 384, 4), blk, 0, stream>>>(
            y1, w_bs_dw, yg, 0, 0, 384, 0, 384, 0, 0, 1);
        for (int h = 0; h < 8; ++h) {
            gemm48<float, bf16><<<dim3(3, 128, 4), blk, 0, stream>>>(
                x, x, 384, 384, 384, 0, 384, 384, 0, 384,
                w_qkv, 3, 384, 48, h * 48, qph, 3, 48, 0, 144, 0);
            dw3x3v<<<dim3(8, 144, 4), blk, 0, stream>>>(
                qph, w_dw, qkvdh, 1, h * 48, 144, 0, 144, 0, 0, 0);
            l2norm_v<<<dim3(2 * 4 * 48), blk, 0, stream>>>(qkvdh, inv, 4);
            qk_mfma<<<dim3(4, 8), blk, 0, stream>>>(qkvdh, lp, 4, 512);
            softmax48<<<dim3(4), blk, 0, stream>>>(lp, inv, abf, 4, 32);
            av_mfma<<<dim3(128, 4), blk, 0, stream>>>(abf, qkvdh, attn, h * 48, 384);
        }
        gemm48<bf16, float><<<dim3(8, 128, 4), blk, 0, stream>>>(
            attn, yg, 384, 768, 384, 0, 384, 384, 0, 384,
            w_proj, 1, 0, 48, 0, out, 1, 0, 48, 384, 0);
    }
}

// Round 6
// 625.255 us; speedup vs baseline: 1.6274x; 1.1898x over previous
//
#include <hip/hip_runtime.h>
#include <hip/hip_bf16.h>
#include <math.h>

typedef __hip_bfloat16 bf16;
typedef short bf16x8 __attribute__((ext_vector_type(8)));
typedef float f32x4 __attribute__((ext_vector_type(4)));

#define NPIX 16384  // 128*128 spatial per channel

static __device__ __forceinline__ float ldv(float v) { return v; }
static __device__ __forceinline__ float ldv(bf16 v) { return __bfloat162float(v); }
static __device__ __forceinline__ float lds16(short s) {
    union { short s_; bf16 h; } u; u.s_ = s; return __bfloat162float(u.h);
}
template <typename T> static __device__ __forceinline__ T stv(float v);
template <> __device__ __forceinline__ float stv<float>(float v) { return v; }
template <> __device__ __forceinline__ bf16 stv<bf16>(float v) { return __float2bfloat16(v); }
static __device__ __forceinline__ short stv16(float v) {
    union { short s_; bf16 h; } u; u.h = __float2bfloat16(v); return u.s_;
}

static __device__ __forceinline__ unsigned pack2f(float a, float b) {
    union { bf16 h; unsigned short u; } ua, ub;
    ua.h = __float2bfloat16(a); ub.h = __float2bfloat16(b);
    return (unsigned)ua.u | ((unsigned)ub.u << 16);
}
static __device__ __forceinline__ unsigned packbb(unsigned short lo, unsigned short hi) {
    return (unsigned)lo | ((unsigned)hi << 16);
}

template <typename SrcT>
static __device__ __forceinline__ const SrcT* maprow(const SrcT* A, const SrcT* B, int k,
    int Ksplit, int agrp, int ags, int abss, int bgrp, int bgs, int bbs, int b)
{
    if (k < Ksplit) return A + (size_t)((k / agrp) * ags + b * abss + (k % agrp)) * NPIX;
    k -= Ksplit;
    return B + (size_t)((k / bgrp) * bgs + b * bbs + (k % bgrp)) * NPIX;
}

// ---------------------------------------------------------------------------
// Pack f32 weights -> bf16, flat. grid: n/2048, block 256.
// ---------------------------------------------------------------------------
__global__ __launch_bounds__(256) void packw(const float* __restrict__ s,
                                             bf16* __restrict__ d, int n)
{
    int i = (blockIdx.x * 256 + threadIdx.x) * 8;
    if (i + 8 > n) return;
    float4 v0 = *(const float4*)(s + i);
    float4 v1 = *(const float4*)(s + i + 4);
    uint4 u;
    u.x = pack2f(v0.x, v0.y); u.y = pack2f(v0.z, v0.w);
    u.z = pack2f(v1.x, v1.y); u.w = pack2f(v1.z, v1.w);
    *(uint4*)(void*)(d + i) = u;
}

// ---------------------------------------------------------------------------
// Transpose x [b][384][16384] f32 -> xT [b][16384][384] bf16.
// Tile 64 px x 384 ch via LDS with 16B-block XOR swizzle. grid: (256, 4)
// ---------------------------------------------------------------------------
__global__ __launch_bounds__(256) void xpose(const float* __restrict__ x,
                                             bf16* __restrict__ xT)
{
    __shared__ short Ls[64 * 384];
    const int t = threadIdx.x;
    const int px0 = blockIdx.x * 64;
    const int b = blockIdx.y;
    const float* xb = x + (size_t)b * 384 * NPIX;

#pragma unroll 4
    for (int i = 0; i < 24; ++i) {
        int e = i * 256 + t;
        int ch = e >> 4, seg = e & 15;
        float4 v = *(const float4*)(xb + (size_t)ch * NPIX + px0 + seg * 4);
        const float* vp = (const float*)&v;
#pragma unroll
        for (int j = 0; j < 4; ++j) {
            int px = seg * 4 + j;
            int B = (ch >> 3) ^ ((px >> 2) & 7);
            Ls[px * 384 + B * 8 + (ch & 7)] = stv16(vp[j]);
        }
    }
    __syncthreads();

    const int lpx = t >> 2;
    const int m = (lpx >> 2) & 7;
    bf16* ob = xT + ((size_t)b * NPIX + px0 + lpx) * 384;
#pragma unroll
    for (int j = 0; j < 12; ++j) {
        int B = (t & 3) + j * 4;
        bf16x8 blk = *(const bf16x8*)&Ls[lpx * 384 + (B ^ m) * 8];
        *(bf16x8*)(void*)(ob + B * 8) = blk;
    }
}

// ---------------------------------------------------------------------------
// Transpose bf16 ch-major [b][384][16K] -> px-major pxT[b][16K][768] upper half
// (ch offset +384). Same LDS swizzle as xpose. grid: (256, 4)
// ---------------------------------------------------------------------------
__global__ __launch_bounds__(256) void xposeB(const bf16* __restrict__ src,
                                              bf16* __restrict__ dst)
{
    __shared__ short Ls[64 * 384];
    const int t = threadIdx.x;
    const int px0 = blockIdx.x * 64;
    const int b = blockIdx.y;
    const bf16* sb = src + (size_t)b * 384 * NPIX;

#pragma unroll 4
    for (int i = 0; i < 12; ++i) {
        int e = i * 256 + t;               // 3072 x 16B loads
        int ch = e >> 3, seg = e & 7;
        bf16x8 v = *(const bf16x8*)(const void*)(sb + (size_t)ch * NPIX + px0 + seg * 8);
#pragma unroll
        for (int j = 0; j < 8; ++j) {
            int px = seg * 8 + j;
            int B = (ch >> 3) ^ ((px >> 2) & 7);
            Ls[px * 384 + B * 8 + (ch & 7)] = v[j];
        }
    }
    __syncthreads();

    const int lpx = t >> 2;
    const int m = (lpx >> 2) & 7;
    bf16* ob = dst + ((size_t)b * NPIX + px0 + lpx) * 768 + 384;
#pragma unroll
    for (int j = 0; j < 12; ++j) {
        int B = (t & 3) + j * 4;
        bf16x8 blk = *(const bf16x8*)&Ls[lpx * 384 + (B ^ m) * 8];
        *(bf16x8*)(void*)(ob + B * 8) = blk;
    }
}

// ---------------------------------------------------------------------------
// gemm3: m97-style LDS double-buffered MFMA GEMM, B already px-major.
// ---------------------------------------------------------------------------
template <int BM, int K, typename OutT>
__global__ __launch_bounds__(256) void gemm3(
    const bf16* __restrict__ wp, int G, int wsA, int wrowMul,
    const bf16* __restrict__ bsrc,
    OutT* __restrict__ out, int osA, int obS,
    int bmCount, int nwg)
{
    constexpr int MT = BM / 16;       // m-tiles
    constexpr int S  = K / 32;        // K-steps
    constexpr int ACH = BM * 4;       // 16B A-chunks per step
    __shared__ __align__(16) short As[2][BM * 40];
    __shared__ __align__(16) short Bs[2][128 * 40];

    const int t = threadIdx.x;
    const int gid = blockIdx.x;
    const int w = (gid & 7) * (nwg >> 3) + (gid >> 3);
    const int bm = w % bmCount, grp = w / bmCount;
    const int b = grp & 3, px0 = (grp >> 2) * 128;

    const int l = t & 63, wvid = t >> 6, l15 = l & 15, q = l >> 4;
    const int wr0 = bm * wrowMul;
    const size_t bRow0 = (size_t)b * NPIX + px0;

    const int e0 = t,        r0 = e0 >> 2, c0 = e0 & 3;
    const int e1 = t + 256,  r1 = e1 >> 2, c1 = e1 & 3;
    const bf16* apt0 = wp + (size_t)(wr0 + (r0 / G) * wsA + (r0 % G)) * K + c0 * 8;
    const bf16* apt1 = wp + (size_t)(wr0 + (r1 / G) * wsA + (r1 % G)) * K + c1 * 8;
    const int sA0 = r0 * 40 + c0 * 8, sA1 = r1 * 40 + c1 * 8;
    const bf16* apt2 = apt0; int sA2 = sA0; bool has2 = false;
    if constexpr (ACH > 512) {
        if (t < ACH - 512) {
            int e2 = t + 512, r2 = e2 >> 2, c2 = e2 & 3;
            apt2 = wp + (size_t)(wr0 + (r2 / G) * wsA + (r2 % G)) * K + c2 * 8;
            sA2 = r2 * 40 + c2 * 8;
            has2 = true;
        }
    }
    const bf16* bpt0 = bsrc + (bRow0 + r0) * K + c0 * 8;
    const bf16* bpt1 = bsrc + (bRow0 + r1) * K + c1 * 8;

    f32x4 acc[MT][2];
#pragma unroll
    for (int mt = 0; mt < MT; ++mt)
#pragma unroll
        for (int nt = 0; nt < 2; ++nt) acc[mt][nt] = (f32x4){0.f, 0.f, 0.f, 0.f};

    bf16x8 aR0, aR1, aR2, bR0, bR1;

    auto GLOADS = [&](int kk) {
        aR0 = *(const bf16x8*)(const void*)(apt0 + kk);
        aR1 = *(const bf16x8*)(const void*)(apt1 + kk);
        if constexpr (ACH > 512) { if (has2) aR2 = *(const bf16x8*)(const void*)(apt2 + kk); }
        bR0 = *(const bf16x8*)(const void*)(bpt0 + kk);
        bR1 = *(const bf16x8*)(const void*)(bpt1 + kk);
    };
    auto SSTORES = [&](int buf) {
        *(bf16x8*)&As[buf][sA0] = aR0;
        *(bf16x8*)&As[buf][sA1] = aR1;
        if constexpr (ACH > 512) { if (has2) *(bf16x8*)&As[buf][sA2] = aR2; }
        *(bf16x8*)&Bs[buf][sA0] = bR0;
        *(bf16x8*)&Bs[buf][sA1] = bR1;
    };

    GLOADS(0);
    SSTORES(0);
    __syncthreads();

#pragma unroll
    for (int s = 0; s < S; ++s) {
        const int cur = s & 1;
        if (s + 1 < S) GLOADS((s + 1) * 32);
        bf16x8 af[MT], bfv[2];
#pragma unroll
        for (int mt = 0; mt < MT; ++mt)
            af[mt] = *(const bf16x8*)&As[cur][(mt * 16 + l15) * 40 + q * 8];
#pragma unroll
        for (int nt = 0; nt < 2; ++nt)
            bfv[nt] = *(const bf16x8*)&Bs[cur][(wvid * 32 + nt * 16 + l15) * 40 + q * 8];
#pragma unroll
        for (int mt = 0; mt < MT; ++mt)
#pragma unroll
            for (int nt = 0; nt < 2; ++nt)
                acc[mt][nt] = __builtin_amdgcn_mfma_f32_16x16x32_bf16(
                    af[mt], bfv[nt], acc[mt][nt], 0, 0, 0);
        if (s + 1 < S) SSTORES(1 - cur);
        __syncthreads();
    }

    const int obase = bm * osA + b * obS;
#pragma unroll
    for (int mt = 0; mt < MT; ++mt)
#pragma unroll
        for (int nt = 0; nt < 2; ++nt)
#pragma unroll
            for (int r = 0; r < 4; ++r) {
                int row = obase + mt * 16 + q * 4 + r;
                int col = px0 + wvid * 32 + nt * 16 + l15;
                out[(size_t)row * NPIX + col] = stv<OutT>(acc[mt][nt][r]);
            }
}

// ---------------------------------------------------------------------------
// Pipelined MFMA pointwise GEMM (kept for LITE/ULTRA fallback paths)
// ---------------------------------------------------------------------------
template <typename SrcT, typename OutT>
__global__ __launch_bounds__(256) void gemm48(
    const SrcT* __restrict__ srcA, const SrcT* __restrict__ srcB, int Ksplit, int K,
    int agrp, int ags, int abss, int bgrp, int bgs, int bbs,
    const float* __restrict__ w, int wMod, int wsA, int wsB, int wrow0,
    OutT* __restrict__ out, int oMod, int osA, int osB, int obS, int orow0)
{
    __shared__ __align__(16) short As[2][48 * 40];
    __shared__ __align__(16) short Bs[2][128 * 40];

    const int t  = threadIdx.x;
    const int bm = blockIdx.x;
    const int p0 = blockIdx.y * 128;
    const int b  = blockIdx.z;

    const int l = t & 63, wvid = t >> 6, l15 = l & 15, q = l >> 4;
    const int c4 = t >> 4, rp = t & 15;

    const int wbase = wrow0 + (bm % wMod) * wsA + (bm / wMod) * wsB;

    f32x4 acc[3][2];
#pragma unroll
    for (int mt = 0; mt < 3; ++mt)
#pragma unroll
        for (int nt = 0; nt < 2; ++nt) acc[mt][nt] = (f32x4){0.f, 0.f, 0.f, 0.f};

    float aw[6];
    float fb[16];
    bf16x8 hA, hB;

    auto LOADA = [&](int k0) {
#pragma unroll
        for (int i = 0; i < 3; ++i) {
            int idx = t + i * 256, row = idx >> 4, kq = idx & 15;
            float2 v = *(const float2*)(w + (size_t)(wbase + row) * K + k0 + kq * 2);
            aw[2 * i] = v.x; aw[2 * i + 1] = v.y;
        }
    };
    auto STOREA = [&](int buf) {
#pragma unroll
        for (int i = 0; i < 3; ++i) {
            int idx = t + i * 256, row = idx >> 4, kq = idx & 15;
            *(unsigned*)&As[buf][row * 40 + kq * 2] = pack2f(aw[2 * i], aw[2 * i + 1]);
        }
    };
    auto LOADB = [&](int k0) {
        const SrcT* r0 = maprow(srcA, srcB, k0 + 2 * rp,     Ksplit, agrp, ags, abss, bgrp, bgs, bbs, b) + p0 + c4 * 8;
        const SrcT* r1 = maprow(srcA, srcB, k0 + 2 * rp + 1, Ksplit, agrp, ags, abss, bgrp, bgs, bbs, b) + p0 + c4 * 8;
        if constexpr (sizeof(SrcT) == 4) {
            float4 a0 = *(const float4*)r0, a1 = *(const float4*)(r0 + 4);
            float4 b0 = *(const float4*)r1, b1 = *(const float4*)(r1 + 4);
            fb[0] = a0.x; fb[1] = a0.y; fb[2] = a0.z; fb[3] = a0.w;
            fb[4] = a1.x; fb[5] = a1.y; fb[6] = a1.z; fb[7] = a1.w;
            fb[8] = b0.x; fb[9] = b0.y; fb[10] = b0.z; fb[11] = b0.w;
            fb[12] = b1.x; fb[13] = b1.y; fb[14] = b1.z; fb[15] = b1.w;
        } else {
            hA = *(const bf16x8*)(const void*)r0;
            hB = *(const bf16x8*)(const void*)r1;
        }
    };
    auto STOREB = [&](int buf) {
#pragma unroll
        for (int j = 0; j < 8; ++j) {
            unsigned d;
            if constexpr (sizeof(SrcT) == 4) d = pack2f(fb[j], fb[8 + j]);
            else d = packbb((unsigned short)hA[j], (unsigned short)hB[j]);
            *(unsigned*)&Bs[buf][(c4 * 8 + j) * 40 + rp * 2] = d;
        }
    };

    LOADA(0); LOADB(0);
    STOREA(0); STOREB(0);
    const int S = K / 32;
    for (int s = 0; s < S; ++s) {
        const int cur = s & 1;
        __syncthreads();
        if (s + 1 < S) { LOADA((s + 1) * 32); LOADB((s + 1) * 32); }
        bf16x8 af[3], bfr[2];
#pragma unroll
        for (int mt = 0; mt < 3; ++mt)
            af[mt] = *(const bf16x8*)&As[cur][(mt * 16 + l15) * 40 + q * 8];
#pragma unroll
        for (int nt = 0; nt < 2; ++nt)
            bfr[nt] = *(const bf16x8*)&Bs[cur][(wvid * 32 + nt * 16 + l15) * 40 + q * 8];
#pragma unroll
        for (int mt = 0; mt < 3; ++mt)
#pragma unroll
            for (int nt = 0; nt < 2; ++nt)
                acc[mt][nt] = __builtin_amdgcn_mfma_f32_16x16x32_bf16(
                    af[mt], bfr[nt], acc[mt][nt], 0, 0, 0);
        if (s + 1 < S) { STOREA(1 - cur); STOREB(1 - cur); }
    }

    const int obase = orow0 + (bm % oMod) * osA + (bm / oMod) * osB + b * obS;
#pragma unroll
    for (int mt = 0; mt < 3; ++mt)
#pragma unroll
        for (int nt = 0; nt < 2; ++nt)
#pragma unroll
            for (int r = 0; r < 4; ++r) {
                int row = obase + mt * 16 + q * 4 + r;
                int col = p0 + wvid * 32 + nt * 16 + l15;
                out[(size_t)row * NPIX + col] = stv<OutT>(acc[mt][nt][r]);
            }
}

// ---------------------------------------------------------------------------
// Vectorized depthwise 3x3 (+optional exact GELU). 8 px/thread, b128 loads.
// ---------------------------------------------------------------------------
__global__ __launch_bounds__(256) void dw3x3v(
    const bf16* __restrict__ in, const float* __restrict__ w, bf16* __restrict__ out,
    int isQkv, int whofs, int inB, int ig, int outB, int og, int obase, int applyGelu)
{
    const int t = threadIdx.x;
    const int g = blockIdx.x * 256 + t;
    const int c = blockIdx.y;
    const int b = blockIdx.z;
    const int y = g >> 4;
    const int x0 = (g & 15) * 8;

    int inRow, wch, outRow;
    if (isQkv) {
        int h = c / 144, r = c - h * 144;
        inRow  = h * ig + b * inB + r;
        wch    = (r / 48) * 384 + h * 48 + whofs + (r % 48);
        outRow = h * og + b * outB + r + obase;
    } else {
        inRow = b * inB + c; wch = c; outRow = b * outB + c;
    }

    const bf16* ib = in + (size_t)inRow * NPIX;
    float wv[9];
#pragma unroll
    for (int i = 0; i < 9; ++i) wv[i] = w[wch * 9 + i];

    float vv[3][10];
#pragma unroll
    for (int dy = 0; dy < 3; ++dy) {
        int yy = y + dy - 1;
        if (yy < 0 || yy > 127) {
#pragma unroll
            for (int j = 0; j < 10; ++j) vv[dy][j] = 0.f;
        } else {
            const bf16* rb = ib + yy * 128;
            bf16x8 m = *(const bf16x8*)(const void*)(rb + x0);
#pragma unroll
            for (int j = 0; j < 8; ++j) vv[dy][j + 1] = lds16(m[j]);
            vv[dy][0] = (x0 > 0)   ? ldv(rb[x0 - 1]) : 0.f;
            vv[dy][9] = (x0 < 120) ? ldv(rb[x0 + 8]) : 0.f;
        }
    }
    bf16x8 res;
#pragma unroll
    for (int j = 0; j < 8; ++j) {
        float a = 0.f;
#pragma unroll
        for (int dy = 0; dy < 3; ++dy)
#pragma unroll
            for (int dx = 0; dx < 3; ++dx)
                a += wv[dy * 3 + dx] * vv[dy][j + dx];
        if (applyGelu) a = 0.5f * a * (1.0f + erff(a * 0.70710678118654752f));
        res[j] = stv16(a);
    }
    *(bf16x8*)(void*)(out + (size_t)outRow * NPIX + y * 128 + x0) = res;
}

// ---------------------------------------------------------------------------
// inv-L2-norm, vectorized. grid: 2*NBH*48 blocks over qkvd [bh][144][p].
// ---------------------------------------------------------------------------
__global__ __launch_bounds__(256) void l2norm_v(const bf16* __restrict__ qkvd,
                                                float* __restrict__ inv, int NBH)
{
    const int id = blockIdx.x;
    const int which = id / (NBH * 48);
    const int rem = id - which * NBH * 48;
    const int bh = rem / 48, c = rem - bh * 48;
    const bf16* base = qkvd + (size_t)(bh * 144 + which * 48 + c) * NPIX;

    float s = 0.f;
#pragma unroll
    for (int it = 0; it < 8; ++it) {
        bf16x8 v = *(const bf16x8*)(const void*)(base + ((size_t)threadIdx.x + it * 256) * 8);
#pragma unroll
        for (int j = 0; j < 8; ++j) { float f = lds16(v[j]); s += f * f; }
    }
#pragma unroll
    for (int off = 32; off; off >>= 1) s += __shfl_down(s, off, 64);
    __shared__ float partial[4];
    if ((threadIdx.x & 63) == 0) partial[threadIdx.x >> 6] = s;
    __syncthreads();
    if (threadIdx.x == 0) {
        float tt = partial[0] + partial[1] + partial[2] + partial[3];
        inv[(which * NBH + bh) * 48 + c] = 1.0f / fmaxf(sqrtf(tt), 1e-12f);
    }
}

// ---------------------------------------------------------------------------
// QK^T logits partials via MFMA, direct-from-global fragments.
// ---------------------------------------------------------------------------
__global__ __launch_bounds__(256) void qk_mfma(const bf16* __restrict__ qkvd,
                                               float* __restrict__ lp, int NBH, int pxs)
{
    const int bh = blockIdx.x;
    const int wvid = threadIdx.x >> 6;
    const int slice = blockIdx.y * 4 + wvid;
    const int l = threadIdx.x & 63, l15 = l & 15, q = l >> 4;

    const bf16* qb = qkvd + (size_t)(bh * 144) * NPIX;
    const bf16* kb = qb + (size_t)48 * NPIX;

    f32x4 acc[3][3];
#pragma unroll
    for (int mt = 0; mt < 3; ++mt)
#pragma unroll
        for (int nt = 0; nt < 3; ++nt) acc[mt][nt] = (f32x4){0.f, 0.f, 0.f, 0.f};

    const int pbeg = slice * pxs;
    for (int kk = 0; kk < pxs; kk += 32) {
        const int pc = pbeg + kk + q * 8;
        bf16x8 af[3], bfv[3];
#pragma unroll
        for (int mt = 0; mt < 3; ++mt)
            af[mt] = *(const bf16x8*)(const void*)(qb + (size_t)(mt * 16 + l15) * NPIX + pc);
#pragma unroll
        for (int nt = 0; nt < 3; ++nt)
            bfv[nt] = *(const bf16x8*)(const void*)(kb + (size_t)(nt * 16 + l15) * NPIX + pc);
#pragma unroll
        for (int mt = 0; mt < 3; ++mt)
#pragma unroll
            for (int nt = 0; nt < 3; ++nt)
                acc[mt][nt] = __builtin_amdgcn_mfma_f32_16x16x32_bf16(
                    af[mt], bfv[nt], acc[mt][nt], 0, 0, 0);
    }
    float* o = lp + ((size_t)slice * NBH + bh) * 2304;
#pragma unroll
    for (int mt = 0; mt < 3; ++mt)
#pragma unroll
        for (int nt = 0; nt < 3; ++nt)
#pragma unroll
            for (int r = 0; r < 4; ++r)
                o[(mt * 16 + q * 4 + r) * 48 + nt * 16 + l15] = acc[mt][nt][r];
}

// ---------------------------------------------------------------------------
// logit_reduce: sum NSL slice partials with full TLP (coalesced), apply
// scale*invq*invk, write L[bh][2304] f32. grid: (NBH*9), block 256.
// ---------------------------------------------------------------------------
__global__ __launch_bounds__(256) void logit_reduce(const float* __restrict__ lp,
                                                    const float* __restrict__ inv,
                                                    float* __restrict__ L,
                                                    int NBH, int NSL)
{
    const int blk = blockIdx.x;
    const int bh = blk / 9, chunk = blk - bh * 9;
    const int e = chunk * 256 + threadIdx.x;
    float s = 0.f;
    for (int sl = 0; sl < NSL; ++sl)
        s += lp[((size_t)sl * NBH + bh) * 2304 + e];
    const int i = e / 48, j = e - i * 48;
    L[(size_t)bh * 2304 + e] =
        s * 0.14433756729740643f * inv[bh * 48 + i] * inv[(NBH + bh) * 48 + j];
}

// ---------------------------------------------------------------------------
// softmax48b: row-softmax of precomputed L[bh][2304], emit bf16 a_bf
// (zero-padded K to 64). grid: (NBH)
// ---------------------------------------------------------------------------
__global__ __launch_bounds__(256) void softmax48b(const float* __restrict__ Lg,
                                                  bf16* __restrict__ a_bf)
{
    const int bh = blockIdx.x, t = threadIdx.x;
    __shared__ float L[2304];
    for (int e = t; e < 2304; e += 256) L[e] = Lg[(size_t)bh * 2304 + e];
    __syncthreads();
    if (t < 48) {
        float m = -1e30f;
#pragma unroll
        for (int j = 0; j < 48; ++j) m = fmaxf(m, L[t * 48 + j]);
        float e_[48]; float ssum = 0.f;
#pragma unroll
        for (int j = 0; j < 48; ++j) { e_[j] = expf(L[t * 48 + j] - m); ssum += e_[j]; }
        float r = 1.f / ssum;
        bf16* ab = a_bf + (size_t)bh * 3072 + t * 64;
#pragma unroll
        for (int j = 0; j < 48; ++j) ab[j] = stv<bf16>(e_[j] * r);
#pragma unroll
        for (int j = 48; j < 64; ++j) ab[j] = stv<bf16>(0.f);
    }
}

// ---------------------------------------------------------------------------
// Sum NSL slice-partials, apply scale*invq*invk, row-softmax, emit bf16.
// (LITE/ULTRA fallback paths)
// ---------------------------------------------------------------------------
__global__ __launch_bounds__(256) void softmax48(const float* __restrict__ lp,
                                                 const float* __restrict__ inv,
                                                 bf16* __restrict__ a_bf, int NBH, int NSL)
{
    const int bh = blockIdx.x, t = threadIdx.x;
    __shared__ float L[2304];
    for (int e = t; e < 2304; e += 256) {
        float s = 0.f;
        for (int sl = 0; sl < NSL; ++sl) s += lp[((size_t)sl * NBH + bh) * 2304 + e];
        int i = e / 48, j = e - i * 48;
        L[e] = s * 0.14433756729740643f * inv[bh * 48 + i] * inv[(NBH + bh) * 48 + j];
    }
    __syncthreads();
    if (t < 48) {
        float m = -1e30f;
#pragma unroll
        for (int j = 0; j < 48; ++j) m = fmaxf(m, L[t * 48 + j]);
        float e_[48]; float ssum = 0.f;
#pragma unroll
        for (int j = 0; j < 48; ++j) { e_[j] = expf(L[t * 48 + j] - m); ssum += e_[j]; }
        float r = 1.f / ssum;
        bf16* ab = a_bf + (size_t)bh * 3072 + t * 64;
#pragma unroll
        for (int j = 0; j < 48; ++j) ab[j] = stv<bf16>(e_[j] * r);
#pragma unroll
        for (int j = 48; j < 64; ++j) ab[j] = stv<bf16>(0.f);
    }
}

// ---------------------------------------------------------------------------
// AV via MFMA, ch-major output (LITE/ULTRA paths).
// ---------------------------------------------------------------------------
__global__ __launch_bounds__(256) void av_mfma(const bf16* __restrict__ a_bf,
                                               const bf16* __restrict__ qkvd,
                                               bf16* __restrict__ out, int obase, int oS)
{
    __shared__ __align__(16) short Bs[128 * 72];
    const int t = threadIdx.x;
    const int px0 = blockIdx.x * 128;
    const int bh = blockIdx.y;
    const int l = t & 63, wvid = t >> 6, l15 = l & 15, q = l >> 4;
    const int c4 = t >> 4, rp = t & 15;

    const bf16* ab = a_bf + (size_t)bh * 3072;
    bf16x8 af[3][2];
#pragma unroll
    for (int mt = 0; mt < 3; ++mt)
#pragma unroll
        for (int kq = 0; kq < 2; ++kq)
            af[mt][kq] = *(const bf16x8*)(const void*)(ab + (mt * 16 + l15) * 64 + kq * 32 + q * 8);

    const bf16* vb = qkvd + (size_t)(bh * 144 + 96) * NPIX;
    bf16x8 vr[4];
#pragma unroll
    for (int jj = 0; jj < 4; ++jj) {
        int j = rp * 4 + jj; int jc = j < 48 ? j : 47;
        vr[jj] = *(const bf16x8*)(const void*)(vb + (size_t)jc * NPIX + px0 + c4 * 8);
    }
#pragma unroll
    for (int j = 0; j < 8; ++j) {
        *(unsigned*)&Bs[(c4 * 8 + j) * 72 + rp * 4]     = packbb((unsigned short)vr[0][j], (unsigned short)vr[1][j]);
        *(unsigned*)&Bs[(c4 * 8 + j) * 72 + rp * 4 + 2] = packbb((unsigned short)vr[2][j], (unsigned short)vr[3][j]);
    }
    __syncthreads();

    f32x4 acc[3][2];
#pragma unroll
    for (int mt = 0; mt < 3; ++mt)
#pragma unroll
        for (int nt = 0; nt < 2; ++nt) acc[mt][nt] = (f32x4){0.f, 0.f, 0.f, 0.f};

    bf16x8 bfv[2][2];
#pragma unroll
    for (int nt = 0; nt < 2; ++nt)
#pragma unroll
        for (int kq = 0; kq < 2; ++kq)
            bfv[nt][kq] = *(const bf16x8*)&Bs[(wvid * 32 + nt * 16 + l15) * 72 + kq * 32 + q * 8];
#pragma unroll
    for (int kq = 0; kq < 2; ++kq)
#pragma unroll
        for (int mt = 0; mt < 3; ++mt)
#pragma unroll
            for (int nt = 0; nt < 2; ++nt)
                acc[mt][nt] = __builtin_amdgcn_mfma_f32_16x16x32_bf16(
                    af[mt][kq], bfv[nt][kq], acc[mt][nt], 0, 0, 0);
#pragma unroll
    for (int mt = 0; mt < 3; ++mt)
#pragma unroll
        for (int nt = 0; nt < 2; ++nt)
#pragma unroll
            for (int r = 0; r < 4; ++r) {
                int row = obase + bh * oS + mt * 16 + q * 4 + r;
                int col = px0 + wvid * 32 + nt * 16 + l15;
                out[(size_t)row * NPIX + col] = stv<bf16>(acc[mt][nt][r]);
            }
}

// ---------------------------------------------------------------------------
// AV via MFMA, px-major output into pxT[b][16K][768] lower half (ch h*48+c).
// grid: (128, NBH=32)
// ---------------------------------------------------------------------------
__global__ __launch_bounds__(256) void av_mfma2(const bf16* __restrict__ a_bf,
                                                const bf16* __restrict__ qkvd,
                                                bf16* __restrict__ pxT)
{
    __shared__ __align__(16) short Bs[128 * 72];
    const int t = threadIdx.x;
    const int px0 = blockIdx.x * 128;
    const int bh = blockIdx.y;
    const int l = t & 63, wvid = t >> 6, l15 = l & 15, q = l >> 4;
    const int c4 = t >> 4, rp = t & 15;

    const bf16* ab = a_bf + (size_t)bh * 3072;
    bf16x8 af[3][2];
#pragma unroll
    for (int mt = 0; mt < 3; ++mt)
#pragma unroll
        for (int kq = 0; kq < 2; ++kq)
            af[mt][kq] = *(const bf16x8*)(const void*)(ab + (mt * 16 + l15) * 64 + kq * 32 + q * 8);

    const bf16* vb = qkvd + (size_t)(bh * 144 + 96) * NPIX;
    bf16x8 vr[4];
#pragma unroll
    for (int jj = 0; jj < 4; ++jj) {
        int j = rp * 4 + jj; int jc = j < 48 ? j : 47;
        vr[jj] = *(const bf16x8*)(const void*)(vb + (size_t)jc * NPIX + px0 + c4 * 8);
    }
#pragma unroll
    for (int j = 0; j < 8; ++j) {
        *(unsigned*)&Bs[(c4 * 8 + j) * 72 + rp * 4]     = packbb((unsigned short)vr[0][j], (unsigned short)vr[1][j]);
        *(unsigned*)&Bs[(c4 * 8 + j) * 72 + rp * 4 + 2] = packbb((unsigned short)vr[2][j], (unsigned short)vr[3][j]);
    }
    __syncthreads();

    f32x4 acc[3][2];
#pragma unroll
    for (int mt = 0; mt < 3; ++mt)
#pragma unroll
        for (int nt = 0; nt < 2; ++nt) acc[mt][nt] = (f32x4){0.f, 0.f, 0.f, 0.f};

    bf16x8 bfv[2][2];
#pragma unroll
    for (int nt = 0; nt < 2; ++nt)
#pragma unroll
        for (int kq = 0; kq < 2; ++kq)
            bfv[nt][kq] = *(const bf16x8*)&Bs[(wvid * 32 + nt * 16 + l15) * 72 + kq * 32 + q * 8];
#pragma unroll
    for (int kq = 0; kq < 2; ++kq)
#pragma unroll
        for (int mt = 0; mt < 3; ++mt)
#pragma unroll
            for (int nt = 0; nt < 2; ++nt)
                acc[mt][nt] = __builtin_amdgcn_mfma_f32_16x16x32_bf16(
                    af[mt][kq], bfv[nt][kq], acc[mt][nt], 0, 0, 0);

    // transpose acc -> Bs[pxl][48ch] bf16, then coalesced px-major stores
    __syncthreads();
#pragma unroll
    for (int mt = 0; mt < 3; ++mt)
#pragma unroll
        for (int nt = 0; nt < 2; ++nt) {
            int pxl = wvid * 32 + nt * 16 + l15;
#pragma unroll
            for (int r = 0; r < 2; ++r)
                *(unsigned*)&Bs[pxl * 48 + mt * 16 + q * 4 + r * 2] =
                    pack2f(acc[mt][nt][2 * r], acc[mt][nt][2 * r + 1]);
        }
    __syncthreads();

    const int h = bh >> 2, bb = bh & 3;
    const int pxl = t >> 1, half = t & 1;
    bf16* ob = pxT + ((size_t)bb * NPIX + px0 + pxl) * 768 + h * 48 + half * 24;
#pragma unroll
    for (int j = 0; j < 3; ++j)
        *(bf16x8*)(void*)(ob + j * 8) = *(const bf16x8*)&Bs[pxl * 48 + half * 24 + j * 8];
}

// ---------------------------------------------------------------------------
extern "C" void kernel_launch(void* const* d_in, const int* in_sizes, int n_in,
                              void* d_out, int out_size, void* d_ws, size_t ws_size,
                              hipStream_t stream) {
    const float* x       = (const float*)d_in[0];
    const float* w_qkv   = (const float*)d_in[1];
    const float* w_dw    = (const float*)d_in[2];
    const float* w_proj  = (const float*)d_in[3];
    const float* w_bs_pw = (const float*)d_in[4];
    const float* w_bs_dw = (const float*)d_in[5];
    float* out = (float*)d_out;
    bf16* y1 = (bf16*)d_out;  // bs_pw bf16 output lives in d_out space until proj

    const size_t SZQ = 150994944ull;  // 8h*4b*144*16384*2
    const size_t SZH = 18874368ull;   // 4b*144*16384*2
    const size_t SZY = 50331648ull;   // 4b*384*16384*2
    const size_t SZPXT = 100663296ull; // 4b*16384*768*2
    char* ws = (char*)d_ws;
    dim3 blk(256);

    if (ws_size >= 371404800ull) {
        // ---------- FULL: all heads batched ----------
        bf16* qkvp = (bf16*)ws;
        bf16* pxT  = (bf16*)ws;
        bf16* wprojp = (bf16*)(ws + SZPXT);
        float* Lbuf  = (float*)(ws + SZPXT + 1048576ull);  // 294912 B, dead-qkvp gap
        bf16* qkvd = (bf16*)(ws + SZQ);
        bf16* xT   = (bf16*)(ws + 2 * SZQ);
        bf16* yg   = xT;
        float* lp  = (float*)(ws + 2 * SZQ + SZY);
        bf16* wqkvp = (bf16*)lp;
        bf16* wbsp  = (bf16*)((char*)lp + 884736ull);
        bf16* abf  = (bf16*)(ws + 2 * SZQ + SZY + 18874368ull);
        float* inv = (float*)(ws + 2 * SZQ + SZY + 18874368ull + 196608ull);

        packw<<<dim3(216), blk, 0, stream>>>(w_qkv, wqkvp, 442368);
        packw<<<dim3(72), blk, 0, stream>>>(w_bs_pw, wbsp, 147456);
        xpose<<<dim3(256, 4), blk, 0, stream>>>(x, xT);
        gemm3<144, 384, bf16><<<dim3(4096), blk, 0, stream>>>(
            wqkvp, 48, 384, 48, xT, qkvp, 576, 144, 8, 4096);
        dw3x3v<<<dim3(8, 1152, 4), blk, 0, stream>>>(
            qkvp, w_dw, qkvd, 1, 0, 144, 576, 144, 576, 0, 0);
        packw<<<dim3(144), blk, 0, stream>>>(w_proj, wprojp, 294912);  // qkvp dead
        gemm3<128, 384, bf16><<<dim3(1536), blk, 0, stream>>>(
            wbsp, 128, 0, 128, xT, y1, 128, 384, 3, 1536);
        dw3x3v<<<dim3(8, 384, 4), blk, 0, stream>>>(
            y1, w_bs_dw, yg, 0, 0, 384, 0, 384, 0, 0, 1);          // xT dead, yg over it
        xposeB<<<dim3(256, 4), blk, 0, stream>>>(yg, pxT);         // yg -> pxT[.., 384:768]
        l2norm_v<<<dim3(2 * 32 * 48), blk, 0, stream>>>(qkvd, inv, 32);
        qk_mfma<<<dim3(32, 16), blk, 0, stream>>>(qkvd, lp, 32, 256);
        logit_reduce<<<dim3(32 * 9), blk, 0, stream>>>(lp, inv, Lbuf, 32, 64);
        softmax48b<<<dim3(32), blk, 0, stream>>>(Lbuf, abf);
        av_mfma2<<<dim3(128, 32), blk, 0, stream>>>(abf, qkvd, pxT); // -> pxT[.., 0:384]
        gemm3<128, 768, float><<<dim3(1536), blk, 0, stream>>>(
            wprojp, 128, 0, 128, pxT, out, 128, 384, 3, 1536);
    } else if (ws_size >= 239284224ull) {
        // ---------- LITE: per-head pw+dw, rest batched ----------
        bf16* qkvd = (bf16*)ws;
        bf16* qph  = (bf16*)(ws + SZQ);
        bf16* yg   = (bf16*)(ws + SZQ + SZH);
        float* lp  = (float*)(ws + SZQ + SZH + SZY);
        bf16* abf  = (bf16*)(ws + SZQ + SZH + SZY + 18874368ull);
        float* inv = (float*)(ws + SZQ + SZH + SZY + 18874368ull + 196608ull);

        for (int h = 0; h < 8; ++h) {
            gemm48<float, bf16><<<dim3(3, 128, 4), blk, 0, stream>>>(
                x, x, 384, 384, 384, 0, 384, 384, 0, 384,
                w_qkv, 3, 384, 48, h * 48, qph, 3, 48, 0, 144, 0);
            dw3x3v<<<dim3(8, 144, 4), blk, 0, stream>>>(
                qph, w_dw, qkvd, 1, h * 48, 144, 0, 144, 0, h * 576, 0);
        }
        l2norm_v<<<dim3(2 * 32 * 48), blk, 0, stream>>>(qkvd, inv, 32);
        qk_mfma<<<dim3(32, 16), blk, 0, stream>>>(qkvd, lp, 32, 256);
        softmax48<<<dim3(32), blk, 0, stream>>>(lp, inv, abf, 32, 64);
        gemm48<float, bf16><<<dim3(8, 128, 4), blk, 0, stream>>>(
            x, x, 384, 384, 384, 0, 384, 384, 0, 384,
            w_bs_pw, 1, 0, 48, 0, y1, 1, 0, 48, 384, 0);
        dw3x3v<<<dim3(8, 384, 4), blk, 0, stream>>>(
            y1, w_bs_dw, yg, 0, 0, 384, 0, 384, 0, 0, 1);
        av_mfma<<<dim3(128, 32), blk, 0, stream>>>(abf, qkvd, qkvd, 0, 144);
        gemm48<bf16, float><<<dim3(8, 128, 4), blk, 0, stream>>>(
            qkvd, yg, 384, 768, 48, 576, 144, 384, 0, 384,
            w_proj, 1, 0, 48, 0, out, 1, 0, 48, 384, 0);
    } else {
        // ---------- ULTRA: fully per-head (~139.6 MB) ----------
        bf16* qph   = (bf16*)ws;
        bf16* qkvdh = (bf16*)(ws + SZH);
        bf16* yg    = (bf16*)(ws + 2 * SZH);
        bf16* attn  = (bf16*)(ws + 2 * SZH + SZY);
        float* lp   = (float*)(ws + 2 * SZH + 2 * SZY);
        bf16* abf   = (bf16*)(ws + 2 * SZH + 2 * SZY + 1179648ull);
        float* inv  = (float*)(ws + 2 * SZH + 2 * SZY + 1179648ull + 24576ull);

        gemm48<float, bf16><<<dim3(8, 128, 4), blk, 0, stream>>>(
            x, x, 384, 384, 384, 0, 384, 384, 0, 384,
            w_bs_pw, 1, 0, 48, 0, y1, 1, 0, 48, 384, 0);
        dw3x3v<<<dim3(8, 384, 4), blk, 0, stream>>>(
            y1, w_bs_dw, yg, 0, 0, 384, 0, 384, 0, 0, 1);
        for (int h = 0; h < 8; ++h) {
            gemm48<float, bf16><<<dim3(3, 128, 4), blk, 0, stream>>>(
                x, x, 384, 384, 384, 0, 384, 384, 0, 384,
                w_qkv, 3, 384, 48, h * 48, qph, 3, 48, 0, 144, 0);
            dw3x3v<<<dim3(8, 144, 4), blk, 0, stream>>>(
                qph, w_dw, qkvdh, 1, h * 48, 144, 0, 144, 0, 0, 0);
            l2norm_v<<<dim3(2 * 4 * 48), blk, 0, stream>>>(qkvdh, inv, 4);
            qk_mfma<<<dim3(4, 8), blk, 0, stream>>>(qkvdh, lp, 4, 512);
            softmax48<<<dim3(4), blk, 0, stream>>>(lp, inv, abf, 4, 32);
            av_mfma<<<dim3(128, 4), blk, 0, stream>>>(abf, qkvdh, attn, h * 48, 384);
        }
        gemm48<bf16, float><<<dim3(8, 128, 4), blk, 0, stream>>>(
            attn, yg, 384, 768, 384, 0, 384, 384, 0, 384,
            w_proj, 1, 0, 48, 0, out, 1, 0, 48, 384, 0);
    }
}

// Round 7
// 582.504 us; speedup vs baseline: 1.7469x; 1.0734x over previous
//
#include <hip/hip_runtime.h>
#include <hip/hip_bf16.h>
#include <math.h>

typedef __hip_bfloat16 bf16;
typedef short bf16x8 __attribute__((ext_vector_type(8)));
typedef float f32x4 __attribute__((ext_vector_type(4)));

#define NPIX 16384  // 128*128 spatial per channel

static __device__ __forceinline__ float ldv(float v) { return v; }
static __device__ __forceinline__ float ldv(bf16 v) { return __bfloat162float(v); }
static __device__ __forceinline__ float lds16(short s) {
    union { short s_; bf16 h; } u; u.s_ = s; return __bfloat162float(u.h);
}
template <typename T> static __device__ __forceinline__ T stv(float v);
template <> __device__ __forceinline__ float stv<float>(float v) { return v; }
template <> __device__ __forceinline__ bf16 stv<bf16>(float v) { return __float2bfloat16(v); }
static __device__ __forceinline__ short stv16(float v) {
    union { short s_; bf16 h; } u; u.h = __float2bfloat16(v); return u.s_;
}

static __device__ __forceinline__ unsigned pack2f(float a, float b) {
    union { bf16 h; unsigned short u; } ua, ub;
    ua.h = __float2bfloat16(a); ub.h = __float2bfloat16(b);
    return (unsigned)ua.u | ((unsigned)ub.u << 16);
}
static __device__ __forceinline__ unsigned packbb(unsigned short lo, unsigned short hi) {
    return (unsigned)lo | ((unsigned)hi << 16);
}

template <typename SrcT>
static __device__ __forceinline__ const SrcT* maprow(const SrcT* A, const SrcT* B, int k,
    int Ksplit, int agrp, int ags, int abss, int bgrp, int bgs, int bbs, int b)
{
    if (k < Ksplit) return A + (size_t)((k / agrp) * ags + b * abss + (k % agrp)) * NPIX;
    k -= Ksplit;
    return B + (size_t)((k / bgrp) * bgs + b * bbs + (k % bgrp)) * NPIX;
}

// ---------------------------------------------------------------------------
// Pack f32 weights -> bf16, flat. grid: n/2048, block 256.
// ---------------------------------------------------------------------------
__global__ __launch_bounds__(256) void packw(const float* __restrict__ s,
                                             bf16* __restrict__ d, int n)
{
    int i = (blockIdx.x * 256 + threadIdx.x) * 8;
    if (i + 8 > n) return;
    float4 v0 = *(const float4*)(s + i);
    float4 v1 = *(const float4*)(s + i + 4);
    uint4 u;
    u.x = pack2f(v0.x, v0.y); u.y = pack2f(v0.z, v0.w);
    u.z = pack2f(v1.x, v1.y); u.w = pack2f(v1.z, v1.w);
    *(uint4*)(void*)(d + i) = u;
}

__global__ __launch_bounds__(256) void zerok(float* __restrict__ p, int n)
{
    int i = blockIdx.x * 256 + threadIdx.x;
    if (i < n) p[i] = 0.f;
}

__global__ __launch_bounds__(256) void invk(const float* __restrict__ ss,
                                            float* __restrict__ inv, int n)
{
    int i = blockIdx.x * 256 + threadIdx.x;
    if (i < n) inv[i] = 1.f / fmaxf(sqrtf(ss[i]), 1e-12f);
}

// ---------------------------------------------------------------------------
// Transpose x [b][384][16384] f32 -> xT [b][16384][384] bf16.
// Tile 64 px x 384 ch via LDS with 16B-block XOR swizzle. grid: (256, 4)
// ---------------------------------------------------------------------------
__global__ __launch_bounds__(256) void xpose(const float* __restrict__ x,
                                             bf16* __restrict__ xT)
{
    __shared__ short Ls[64 * 384];
    const int t = threadIdx.x;
    const int px0 = blockIdx.x * 64;
    const int b = blockIdx.y;
    const float* xb = x + (size_t)b * 384 * NPIX;

#pragma unroll 4
    for (int i = 0; i < 24; ++i) {
        int e = i * 256 + t;
        int ch = e >> 4, seg = e & 15;
        float4 v = *(const float4*)(xb + (size_t)ch * NPIX + px0 + seg * 4);
        const float* vp = (const float*)&v;
#pragma unroll
        for (int j = 0; j < 4; ++j) {
            int px = seg * 4 + j;
            int B = (ch >> 3) ^ ((px >> 2) & 7);
            Ls[px * 384 + B * 8 + (ch & 7)] = stv16(vp[j]);
        }
    }
    __syncthreads();

    const int lpx = t >> 2;
    const int m = (lpx >> 2) & 7;
    bf16* ob = xT + ((size_t)b * NPIX + px0 + lpx) * 384;
#pragma unroll
    for (int j = 0; j < 12; ++j) {
        int B = (t & 3) + j * 4;
        bf16x8 blk = *(const bf16x8*)&Ls[lpx * 384 + (B ^ m) * 8];
        *(bf16x8*)(void*)(ob + B * 8) = blk;
    }
}

// ---------------------------------------------------------------------------
// Transpose bf16 ch-major [b][384][16K] -> px-major pxT[b][16K][768] upper half
// (ch offset +384). Same LDS swizzle as xpose. grid: (256, 4)
// ---------------------------------------------------------------------------
__global__ __launch_bounds__(256) void xposeB(const bf16* __restrict__ src,
                                              bf16* __restrict__ dst)
{
    __shared__ short Ls[64 * 384];
    const int t = threadIdx.x;
    const int px0 = blockIdx.x * 64;
    const int b = blockIdx.y;
    const bf16* sb = src + (size_t)b * 384 * NPIX;

#pragma unroll 4
    for (int i = 0; i < 12; ++i) {
        int e = i * 256 + t;               // 3072 x 16B loads
        int ch = e >> 3, seg = e & 7;
        bf16x8 v = *(const bf16x8*)(const void*)(sb + (size_t)ch * NPIX + px0 + seg * 8);
#pragma unroll
        for (int j = 0; j < 8; ++j) {
            int px = seg * 8 + j;
            int B = (ch >> 3) ^ ((px >> 2) & 7);
            Ls[px * 384 + B * 8 + (ch & 7)] = v[j];
        }
    }
    __syncthreads();

    const int lpx = t >> 2;
    const int m = (lpx >> 2) & 7;
    bf16* ob = dst + ((size_t)b * NPIX + px0 + lpx) * 768 + 384;
#pragma unroll
    for (int j = 0; j < 12; ++j) {
        int B = (t & 3) + j * 4;
        bf16x8 blk = *(const bf16x8*)&Ls[lpx * 384 + (B ^ m) * 8];
        *(bf16x8*)(void*)(ob + B * 8) = blk;
    }
}

// ---------------------------------------------------------------------------
// gemm3: m97-style LDS double-buffered MFMA GEMM, B already px-major.
// ---------------------------------------------------------------------------
template <int BM, int K, typename OutT>
__global__ __launch_bounds__(256) void gemm3(
    const bf16* __restrict__ wp, int G, int wsA, int wrowMul,
    const bf16* __restrict__ bsrc,
    OutT* __restrict__ out, int osA, int obS,
    int bmCount, int nwg)
{
    constexpr int MT = BM / 16;       // m-tiles
    constexpr int S  = K / 32;        // K-steps
    constexpr int ACH = BM * 4;       // 16B A-chunks per step
    __shared__ __align__(16) short As[2][BM * 40];
    __shared__ __align__(16) short Bs[2][128 * 40];

    const int t = threadIdx.x;
    const int gid = blockIdx.x;
    const int w = (gid & 7) * (nwg >> 3) + (gid >> 3);
    const int bm = w % bmCount, grp = w / bmCount;
    const int b = grp & 3, px0 = (grp >> 2) * 128;

    const int l = t & 63, wvid = t >> 6, l15 = l & 15, q = l >> 4;
    const int wr0 = bm * wrowMul;
    const size_t bRow0 = (size_t)b * NPIX + px0;

    const int e0 = t,        r0 = e0 >> 2, c0 = e0 & 3;
    const int e1 = t + 256,  r1 = e1 >> 2, c1 = e1 & 3;
    const bf16* apt0 = wp + (size_t)(wr0 + (r0 / G) * wsA + (r0 % G)) * K + c0 * 8;
    const bf16* apt1 = wp + (size_t)(wr0 + (r1 / G) * wsA + (r1 % G)) * K + c1 * 8;
    const int sA0 = r0 * 40 + c0 * 8, sA1 = r1 * 40 + c1 * 8;
    const bf16* apt2 = apt0; int sA2 = sA0; bool has2 = false;
    if constexpr (ACH > 512) {
        if (t < ACH - 512) {
            int e2 = t + 512, r2 = e2 >> 2, c2 = e2 & 3;
            apt2 = wp + (size_t)(wr0 + (r2 / G) * wsA + (r2 % G)) * K + c2 * 8;
            sA2 = r2 * 40 + c2 * 8;
            has2 = true;
        }
    }
    const bf16* bpt0 = bsrc + (bRow0 + r0) * K + c0 * 8;
    const bf16* bpt1 = bsrc + (bRow0 + r1) * K + c1 * 8;

    f32x4 acc[MT][2];
#pragma unroll
    for (int mt = 0; mt < MT; ++mt)
#pragma unroll
        for (int nt = 0; nt < 2; ++nt) acc[mt][nt] = (f32x4){0.f, 0.f, 0.f, 0.f};

    bf16x8 aR0, aR1, aR2, bR0, bR1;

    auto GLOADS = [&](int kk) {
        aR0 = *(const bf16x8*)(const void*)(apt0 + kk);
        aR1 = *(const bf16x8*)(const void*)(apt1 + kk);
        if constexpr (ACH > 512) { if (has2) aR2 = *(const bf16x8*)(const void*)(apt2 + kk); }
        bR0 = *(const bf16x8*)(const void*)(bpt0 + kk);
        bR1 = *(const bf16x8*)(const void*)(bpt1 + kk);
    };
    auto SSTORES = [&](int buf) {
        *(bf16x8*)&As[buf][sA0] = aR0;
        *(bf16x8*)&As[buf][sA1] = aR1;
        if constexpr (ACH > 512) { if (has2) *(bf16x8*)&As[buf][sA2] = aR2; }
        *(bf16x8*)&Bs[buf][sA0] = bR0;
        *(bf16x8*)&Bs[buf][sA1] = bR1;
    };

    GLOADS(0);
    SSTORES(0);
    __syncthreads();

#pragma unroll
    for (int s = 0; s < S; ++s) {
        const int cur = s & 1;
        if (s + 1 < S) GLOADS((s + 1) * 32);
        bf16x8 af[MT], bfv[2];
#pragma unroll
        for (int mt = 0; mt < MT; ++mt)
            af[mt] = *(const bf16x8*)&As[cur][(mt * 16 + l15) * 40 + q * 8];
#pragma unroll
        for (int nt = 0; nt < 2; ++nt)
            bfv[nt] = *(const bf16x8*)&Bs[cur][(wvid * 32 + nt * 16 + l15) * 40 + q * 8];
#pragma unroll
        for (int mt = 0; mt < MT; ++mt)
#pragma unroll
            for (int nt = 0; nt < 2; ++nt)
                acc[mt][nt] = __builtin_amdgcn_mfma_f32_16x16x32_bf16(
                    af[mt], bfv[nt], acc[mt][nt], 0, 0, 0);
        if (s + 1 < S) SSTORES(1 - cur);
        __syncthreads();
    }

    const int obase = bm * osA + b * obS;
#pragma unroll
    for (int mt = 0; mt < MT; ++mt)
#pragma unroll
        for (int nt = 0; nt < 2; ++nt)
#pragma unroll
            for (int r = 0; r < 4; ++r) {
                int row = obase + mt * 16 + q * 4 + r;
                int col = px0 + wvid * 32 + nt * 16 + l15;
                out[(size_t)row * NPIX + col] = stv<OutT>(acc[mt][nt][r]);
            }
}

// ---------------------------------------------------------------------------
// Pipelined MFMA pointwise GEMM (kept for LITE/ULTRA fallback paths)
// ---------------------------------------------------------------------------
template <typename SrcT, typename OutT>
__global__ __launch_bounds__(256) void gemm48(
    const SrcT* __restrict__ srcA, const SrcT* __restrict__ srcB, int Ksplit, int K,
    int agrp, int ags, int abss, int bgrp, int bgs, int bbs,
    const float* __restrict__ w, int wMod, int wsA, int wsB, int wrow0,
    OutT* __restrict__ out, int oMod, int osA, int osB, int obS, int orow0)
{
    __shared__ __align__(16) short As[2][48 * 40];
    __shared__ __align__(16) short Bs[2][128 * 40];

    const int t  = threadIdx.x;
    const int bm = blockIdx.x;
    const int p0 = blockIdx.y * 128;
    const int b  = blockIdx.z;

    const int l = t & 63, wvid = t >> 6, l15 = l & 15, q = l >> 4;
    const int c4 = t >> 4, rp = t & 15;

    const int wbase = wrow0 + (bm % wMod) * wsA + (bm / wMod) * wsB;

    f32x4 acc[3][2];
#pragma unroll
    for (int mt = 0; mt < 3; ++mt)
#pragma unroll
        for (int nt = 0; nt < 2; ++nt) acc[mt][nt] = (f32x4){0.f, 0.f, 0.f, 0.f};

    float aw[6];
    float fb[16];
    bf16x8 hA, hB;

    auto LOADA = [&](int k0) {
#pragma unroll
        for (int i = 0; i < 3; ++i) {
            int idx = t + i * 256, row = idx >> 4, kq = idx & 15;
            float2 v = *(const float2*)(w + (size_t)(wbase + row) * K + k0 + kq * 2);
            aw[2 * i] = v.x; aw[2 * i + 1] = v.y;
        }
    };
    auto STOREA = [&](int buf) {
#pragma unroll
        for (int i = 0; i < 3; ++i) {
            int idx = t + i * 256, row = idx >> 4, kq = idx & 15;
            *(unsigned*)&As[buf][row * 40 + kq * 2] = pack2f(aw[2 * i], aw[2 * i + 1]);
        }
    };
    auto LOADB = [&](int k0) {
        const SrcT* r0 = maprow(srcA, srcB, k0 + 2 * rp,     Ksplit, agrp, ags, abss, bgrp, bgs, bbs, b) + p0 + c4 * 8;
        const SrcT* r1 = maprow(srcA, srcB, k0 + 2 * rp + 1, Ksplit, agrp, ags, abss, bgrp, bgs, bbs, b) + p0 + c4 * 8;
        if constexpr (sizeof(SrcT) == 4) {
            float4 a0 = *(const float4*)r0, a1 = *(const float4*)(r0 + 4);
            float4 b0 = *(const float4*)r1, b1 = *(const float4*)(r1 + 4);
            fb[0] = a0.x; fb[1] = a0.y; fb[2] = a0.z; fb[3] = a0.w;
            fb[4] = a1.x; fb[5] = a1.y; fb[6] = a1.z; fb[7] = a1.w;
            fb[8] = b0.x; fb[9] = b0.y; fb[10] = b0.z; fb[11] = b0.w;
            fb[12] = b1.x; fb[13] = b1.y; fb[14] = b1.z; fb[15] = b1.w;
        } else {
            hA = *(const bf16x8*)(const void*)r0;
            hB = *(const bf16x8*)(const void*)r1;
        }
    };
    auto STOREB = [&](int buf) {
#pragma unroll
        for (int j = 0; j < 8; ++j) {
            unsigned d;
            if constexpr (sizeof(SrcT) == 4) d = pack2f(fb[j], fb[8 + j]);
            else d = packbb((unsigned short)hA[j], (unsigned short)hB[j]);
            *(unsigned*)&Bs[buf][(c4 * 8 + j) * 40 + rp * 2] = d;
        }
    };

    LOADA(0); LOADB(0);
    STOREA(0); STOREB(0);
    const int S = K / 32;
    for (int s = 0; s < S; ++s) {
        const int cur = s & 1;
        __syncthreads();
        if (s + 1 < S) { LOADA((s + 1) * 32); LOADB((s + 1) * 32); }
        bf16x8 af[3], bfr[2];
#pragma unroll
        for (int mt = 0; mt < 3; ++mt)
            af[mt] = *(const bf16x8*)&As[cur][(mt * 16 + l15) * 40 + q * 8];
#pragma unroll
        for (int nt = 0; nt < 2; ++nt)
            bfr[nt] = *(const bf16x8*)&Bs[cur][(wvid * 32 + nt * 16 + l15) * 40 + q * 8];
#pragma unroll
        for (int mt = 0; mt < 3; ++mt)
#pragma unroll
            for (int nt = 0; nt < 2; ++nt)
                acc[mt][nt] = __builtin_amdgcn_mfma_f32_16x16x32_bf16(
                    af[mt], bfr[nt], acc[mt][nt], 0, 0, 0);
        if (s + 1 < S) { STOREA(1 - cur); STOREB(1 - cur); }
    }

    const int obase = orow0 + (bm % oMod) * osA + (bm / oMod) * osB + b * obS;
#pragma unroll
    for (int mt = 0; mt < 3; ++mt)
#pragma unroll
        for (int nt = 0; nt < 2; ++nt)
#pragma unroll
            for (int r = 0; r < 4; ++r) {
                int row = obase + mt * 16 + q * 4 + r;
                int col = p0 + wvid * 32 + nt * 16 + l15;
                out[(size_t)row * NPIX + col] = stv<OutT>(acc[mt][nt][r]);
            }
}

// ---------------------------------------------------------------------------
// dw3x3s: depthwise 3x3 (+optional exact GELU), 2 output rows x 8 px per
// thread; halo pixels fetched from neighbor lanes via shfl (16-lane x-groups
// tile one image row; group-boundary lanes are true image edges -> 0).
// Optionally fuses per-channel sum-of-squares (q,k rows) via atomicAdd.
// grid: (4, C, B), block 256.
// ---------------------------------------------------------------------------
__global__ __launch_bounds__(256) void dw3x3s(
    const bf16* __restrict__ in, const float* __restrict__ w, bf16* __restrict__ out,
    int isQkv, int whofs, int inB, int ig, int outB, int og, int obase,
    int applyGelu, float* __restrict__ sumsq, int nbh)
{
    const int t = threadIdx.x;
    const int g = blockIdx.x * 256 + t;   // 0..1023: 2-row x 8-px tiles
    const int c = blockIdx.y;
    const int b = blockIdx.z;
    const int y0 = (g >> 4) * 2;
    const int x0 = (g & 15) * 8;
    const int xl = t & 15;                // lane position within 16-lane x-group

    int inRow, wch, outRow, nidx = -1;
    if (isQkv) {
        int h = c / 144, r = c - h * 144;
        inRow  = h * ig + b * inB + r;
        wch    = (r / 48) * 384 + h * 48 + whofs + (r % 48);
        outRow = h * og + b * outB + r + obase;
        if (r < 96) nidx = ((r / 48) * nbh + (h * 4 + b)) * 48 + (r % 48);
    } else {
        inRow = b * inB + c; wch = c; outRow = b * outB + c;
    }

    const bf16* ib = in + (size_t)inRow * NPIX;
    float wv[9];
#pragma unroll
    for (int i = 0; i < 9; ++i) wv[i] = w[wch * 9 + i];

    float vv[4][10];
#pragma unroll
    for (int dy = 0; dy < 4; ++dy) {
        int yy = y0 + dy - 1;
        bf16x8 m = (bf16x8){0, 0, 0, 0, 0, 0, 0, 0};
        if (yy >= 0 && yy <= 127)
            m = *(const bf16x8*)(const void*)(ib + yy * 128 + x0);
#pragma unroll
        for (int j = 0; j < 8; ++j) vv[dy][j + 1] = lds16(m[j]);
        float lf = __shfl_up(vv[dy][8], 1, 16);
        float rf = __shfl_down(vv[dy][1], 1, 16);
        vv[dy][0] = (xl == 0)  ? 0.f : lf;
        vv[dy][9] = (xl == 15) ? 0.f : rf;
    }

    float ssum = 0.f;
#pragma unroll
    for (int oy = 0; oy < 2; ++oy) {
        bf16x8 res;
#pragma unroll
        for (int j = 0; j < 8; ++j) {
            float a = 0.f;
#pragma unroll
            for (int dy = 0; dy < 3; ++dy)
#pragma unroll
                for (int dx = 0; dx < 3; ++dx)
                    a += wv[dy * 3 + dx] * vv[oy + dy][j + dx];
            if (applyGelu) a = 0.5f * a * (1.0f + erff(a * 0.70710678118654752f));
            ssum += a * a;
            res[j] = stv16(a);
        }
        *(bf16x8*)(void*)(out + (size_t)outRow * NPIX + (y0 + oy) * 128 + x0) = res;
    }

    if (sumsq != nullptr && nidx >= 0) {   // block-uniform condition
#pragma unroll
        for (int off = 32; off; off >>= 1) ssum += __shfl_down(ssum, off, 64);
        __shared__ float sp[4];
        if ((t & 63) == 0) sp[t >> 6] = ssum;
        __syncthreads();
        if (t == 0) atomicAdd(&sumsq[nidx], sp[0] + sp[1] + sp[2] + sp[3]);
    }
}

// ---------------------------------------------------------------------------
// inv-L2-norm, vectorized (LITE/ULTRA paths).
// ---------------------------------------------------------------------------
__global__ __launch_bounds__(256) void l2norm_v(const bf16* __restrict__ qkvd,
                                                float* __restrict__ inv, int NBH)
{
    const int id = blockIdx.x;
    const int which = id / (NBH * 48);
    const int rem = id - which * NBH * 48;
    const int bh = rem / 48, c = rem - bh * 48;
    const bf16* base = qkvd + (size_t)(bh * 144 + which * 48 + c) * NPIX;

    float s = 0.f;
#pragma unroll
    for (int it = 0; it < 8; ++it) {
        bf16x8 v = *(const bf16x8*)(const void*)(base + ((size_t)threadIdx.x + it * 256) * 8);
#pragma unroll
        for (int j = 0; j < 8; ++j) { float f = lds16(v[j]); s += f * f; }
    }
#pragma unroll
    for (int off = 32; off; off >>= 1) s += __shfl_down(s, off, 64);
    __shared__ float partial[4];
    if ((threadIdx.x & 63) == 0) partial[threadIdx.x >> 6] = s;
    __syncthreads();
    if (threadIdx.x == 0) {
        float tt = partial[0] + partial[1] + partial[2] + partial[3];
        inv[(which * NBH + bh) * 48 + c] = 1.0f / fmaxf(sqrtf(tt), 1e-12f);
    }
}

// ---------------------------------------------------------------------------
// QK^T logits partials via MFMA, direct-from-global fragments.
// ---------------------------------------------------------------------------
__global__ __launch_bounds__(256) void qk_mfma(const bf16* __restrict__ qkvd,
                                               float* __restrict__ lp, int NBH, int pxs)
{
    const int bh = blockIdx.x;
    const int wvid = threadIdx.x >> 6;
    const int slice = blockIdx.y * 4 + wvid;
    const int l = threadIdx.x & 63, l15 = l & 15, q = l >> 4;

    const bf16* qb = qkvd + (size_t)(bh * 144) * NPIX;
    const bf16* kb = qb + (size_t)48 * NPIX;

    f32x4 acc[3][3];
#pragma unroll
    for (int mt = 0; mt < 3; ++mt)
#pragma unroll
        for (int nt = 0; nt < 3; ++nt) acc[mt][nt] = (f32x4){0.f, 0.f, 0.f, 0.f};

    const int pbeg = slice * pxs;
    for (int kk = 0; kk < pxs; kk += 32) {
        const int pc = pbeg + kk + q * 8;
        bf16x8 af[3], bfv[3];
#pragma unroll
        for (int mt = 0; mt < 3; ++mt)
            af[mt] = *(const bf16x8*)(const void*)(qb + (size_t)(mt * 16 + l15) * NPIX + pc);
#pragma unroll
        for (int nt = 0; nt < 3; ++nt)
            bfv[nt] = *(const bf16x8*)(const void*)(kb + (size_t)(nt * 16 + l15) * NPIX + pc);
#pragma unroll
        for (int mt = 0; mt < 3; ++mt)
#pragma unroll
            for (int nt = 0; nt < 3; ++nt)
                acc[mt][nt] = __builtin_amdgcn_mfma_f32_16x16x32_bf16(
                    af[mt], bfv[nt], acc[mt][nt], 0, 0, 0);
    }
    float* o = lp + ((size_t)slice * NBH + bh) * 2304;
#pragma unroll
    for (int mt = 0; mt < 3; ++mt)
#pragma unroll
        for (int nt = 0; nt < 3; ++nt)
#pragma unroll
            for (int r = 0; r < 4; ++r)
                o[(mt * 16 + q * 4 + r) * 48 + nt * 16 + l15] = acc[mt][nt][r];
}

// ---------------------------------------------------------------------------
// logit_reduce: sum NSL slice partials with full TLP (coalesced), apply
// scale*invq*invk, write L[bh][2304] f32. grid: (NBH*9), block 256.
// ---------------------------------------------------------------------------
__global__ __launch_bounds__(256) void logit_reduce(const float* __restrict__ lp,
                                                    const float* __restrict__ inv,
                                                    float* __restrict__ L,
                                                    int NBH, int NSL)
{
    const int blk = blockIdx.x;
    const int bh = blk / 9, chunk = blk - bh * 9;
    const int e = chunk * 256 + threadIdx.x;
    float s = 0.f;
    for (int sl = 0; sl < NSL; ++sl)
        s += lp[((size_t)sl * NBH + bh) * 2304 + e];
    const int i = e / 48, j = e - i * 48;
    L[(size_t)bh * 2304 + e] =
        s * 0.14433756729740643f * inv[bh * 48 + i] * inv[(NBH + bh) * 48 + j];
}

// ---------------------------------------------------------------------------
// softmax48b: row-softmax of precomputed L[bh][2304], emit bf16 a_bf
// (zero-padded K to 64). grid: (NBH)
// ---------------------------------------------------------------------------
__global__ __launch_bounds__(256) void softmax48b(const float* __restrict__ Lg,
                                                  bf16* __restrict__ a_bf)
{
    const int bh = blockIdx.x, t = threadIdx.x;
    __shared__ float L[2304];
    for (int e = t; e < 2304; e += 256) L[e] = Lg[(size_t)bh * 2304 + e];
    __syncthreads();
    if (t < 48) {
        float m = -1e30f;
#pragma unroll
        for (int j = 0; j < 48; ++j) m = fmaxf(m, L[t * 48 + j]);
        float e_[48]; float ssum = 0.f;
#pragma unroll
        for (int j = 0; j < 48; ++j) { e_[j] = expf(L[t * 48 + j] - m); ssum += e_[j]; }
        float r = 1.f / ssum;
        bf16* ab = a_bf + (size_t)bh * 3072 + t * 64;
#pragma unroll
        for (int j = 0; j < 48; ++j) ab[j] = stv<bf16>(e_[j] * r);
#pragma unroll
        for (int j = 48; j < 64; ++j) ab[j] = stv<bf16>(0.f);
    }
}

// ---------------------------------------------------------------------------
// Sum NSL slice-partials, apply scale*invq*invk, row-softmax, emit bf16.
// (LITE/ULTRA fallback paths)
// ---------------------------------------------------------------------------
__global__ __launch_bounds__(256) void softmax48(const float* __restrict__ lp,
                                                 const float* __restrict__ inv,
                                                 bf16* __restrict__ a_bf, int NBH, int NSL)
{
    const int bh = blockIdx.x, t = threadIdx.x;
    __shared__ float L[2304];
    for (int e = t; e < 2304; e += 256) {
        float s = 0.f;
        for (int sl = 0; sl < NSL; ++sl) s += lp[((size_t)sl * NBH + bh) * 2304 + e];
        int i = e / 48, j = e - i * 48;
        L[e] = s * 0.14433756729740643f * inv[bh * 48 + i] * inv[(NBH + bh) * 48 + j];
    }
    __syncthreads();
    if (t < 48) {
        float m = -1e30f;
#pragma unroll
        for (int j = 0; j < 48; ++j) m = fmaxf(m, L[t * 48 + j]);
        float e_[48]; float ssum = 0.f;
#pragma unroll
        for (int j = 0; j < 48; ++j) { e_[j] = expf(L[t * 48 + j] - m); ssum += e_[j]; }
        float r = 1.f / ssum;
        bf16* ab = a_bf + (size_t)bh * 3072 + t * 64;
#pragma unroll
        for (int j = 0; j < 48; ++j) ab[j] = stv<bf16>(e_[j] * r);
#pragma unroll
        for (int j = 48; j < 64; ++j) ab[j] = stv<bf16>(0.f);
    }
}

// ---------------------------------------------------------------------------
// AV via MFMA, ch-major output (LITE/ULTRA paths).
// ---------------------------------------------------------------------------
__global__ __launch_bounds__(256) void av_mfma(const bf16* __restrict__ a_bf,
                                               const bf16* __restrict__ qkvd,
                                               bf16* __restrict__ out, int obase, int oS)
{
    __shared__ __align__(16) short Bs[128 * 72];
    const int t = threadIdx.x;
    const int px0 = blockIdx.x * 128;
    const int bh = blockIdx.y;
    const int l = t & 63, wvid = t >> 6, l15 = l & 15, q = l >> 4;
    const int c4 = t >> 4, rp = t & 15;

    const bf16* ab = a_bf + (size_t)bh * 3072;
    bf16x8 af[3][2];
#pragma unroll
    for (int mt = 0; mt < 3; ++mt)
#pragma unroll
        for (int kq = 0; kq < 2; ++kq)
            af[mt][kq] = *(const bf16x8*)(const void*)(ab + (mt * 16 + l15) * 64 + kq * 32 + q * 8);

    const bf16* vb = qkvd + (size_t)(bh * 144 + 96) * NPIX;
    bf16x8 vr[4];
#pragma unroll
    for (int jj = 0; jj < 4; ++jj) {
        int j = rp * 4 + jj; int jc = j < 48 ? j : 47;
        vr[jj] = *(const bf16x8*)(const void*)(vb + (size_t)jc * NPIX + px0 + c4 * 8);
    }
#pragma unroll
    for (int j = 0; j < 8; ++j) {
        *(unsigned*)&Bs[(c4 * 8 + j) * 72 + rp * 4]     = packbb((unsigned short)vr[0][j], (unsigned short)vr[1][j]);
        *(unsigned*)&Bs[(c4 * 8 + j) * 72 + rp * 4 + 2] = packbb((unsigned short)vr[2][j], (unsigned short)vr[3][j]);
    }
    __syncthreads();

    f32x4 acc[3][2];
#pragma unroll
    for (int mt = 0; mt < 3; ++mt)
#pragma unroll
        for (int nt = 0; nt < 2; ++nt) acc[mt][nt] = (f32x4){0.f, 0.f, 0.f, 0.f};

    bf16x8 bfv[2][2];
#pragma unroll
    for (int nt = 0; nt < 2; ++nt)
#pragma unroll
        for (int kq = 0; kq < 2; ++kq)
            bfv[nt][kq] = *(const bf16x8*)&Bs[(wvid * 32 + nt * 16 + l15) * 72 + kq * 32 + q * 8];
#pragma unroll
    for (int kq = 0; kq < 2; ++kq)
#pragma unroll
        for (int mt = 0; mt < 3; ++mt)
#pragma unroll
            for (int nt = 0; nt < 2; ++nt)
                acc[mt][nt] = __builtin_amdgcn_mfma_f32_16x16x32_bf16(
                    af[mt][kq], bfv[nt][kq], acc[mt][nt], 0, 0, 0);
#pragma unroll
    for (int mt = 0; mt < 3; ++mt)
#pragma unroll
        for (int nt = 0; nt < 2; ++nt)
#pragma unroll
            for (int r = 0; r < 4; ++r) {
                int row = obase + bh * oS + mt * 16 + q * 4 + r;
                int col = px0 + wvid * 32 + nt * 16 + l15;
                out[(size_t)row * NPIX + col] = stv<bf16>(acc[mt][nt][r]);
            }
}

// ---------------------------------------------------------------------------
// AV via MFMA, px-major output into pxT[b][16K][768] lower half (ch h*48+c).
// grid: (128, NBH=32)
// ---------------------------------------------------------------------------
__global__ __launch_bounds__(256) void av_mfma2(const bf16* __restrict__ a_bf,
                                                const bf16* __restrict__ qkvd,
                                                bf16* __restrict__ pxT)
{
    __shared__ __align__(16) short Bs[128 * 72];
    const int t = threadIdx.x;
    const int px0 = blockIdx.x * 128;
    const int bh = blockIdx.y;
    const int l = t & 63, wvid = t >> 6, l15 = l & 15, q = l >> 4;
    const int c4 = t >> 4, rp = t & 15;

    const bf16* ab = a_bf + (size_t)bh * 3072;
    bf16x8 af[3][2];
#pragma unroll
    for (int mt = 0; mt < 3; ++mt)
#pragma unroll
        for (int kq = 0; kq < 2; ++kq)
            af[mt][kq] = *(const bf16x8*)(const void*)(ab + (mt * 16 + l15) * 64 + kq * 32 + q * 8);

    const bf16* vb = qkvd + (size_t)(bh * 144 + 96) * NPIX;
    bf16x8 vr[4];
#pragma unroll
    for (int jj = 0; jj < 4; ++jj) {
        int j = rp * 4 + jj; int jc = j < 48 ? j : 47;
        vr[jj] = *(const bf16x8*)(const void*)(vb + (size_t)jc * NPIX + px0 + c4 * 8);
    }
#pragma unroll
    for (int j = 0; j < 8; ++j) {
        *(unsigned*)&Bs[(c4 * 8 + j) * 72 + rp * 4]     = packbb((unsigned short)vr[0][j], (unsigned short)vr[1][j]);
        *(unsigned*)&Bs[(c4 * 8 + j) * 72 + rp * 4 + 2] = packbb((unsigned short)vr[2][j], (unsigned short)vr[3][j]);
    }
    __syncthreads();

    f32x4 acc[3][2];
#pragma unroll
    for (int mt = 0; mt < 3; ++mt)
#pragma unroll
        for (int nt = 0; nt < 2; ++nt) acc[mt][nt] = (f32x4){0.f, 0.f, 0.f, 0.f};

    bf16x8 bfv[2][2];
#pragma unroll
    for (int nt = 0; nt < 2; ++nt)
#pragma unroll
        for (int kq = 0; kq < 2; ++kq)
            bfv[nt][kq] = *(const bf16x8*)&Bs[(wvid * 32 + nt * 16 + l15) * 72 + kq * 32 + q * 8];
#pragma unroll
    for (int kq = 0; kq < 2; ++kq)
#pragma unroll
        for (int mt = 0; mt < 3; ++mt)
#pragma unroll
            for (int nt = 0; nt < 2; ++nt)
                acc[mt][nt] = __builtin_amdgcn_mfma_f32_16x16x32_bf16(
                    af[mt][kq], bfv[nt][kq], acc[mt][nt], 0, 0, 0);

    // transpose acc -> Bs[pxl][48ch] bf16, then coalesced px-major stores
    __syncthreads();
#pragma unroll
    for (int mt = 0; mt < 3; ++mt)
#pragma unroll
        for (int nt = 0; nt < 2; ++nt) {
            int pxl = wvid * 32 + nt * 16 + l15;
#pragma unroll
            for (int r = 0; r < 2; ++r)
                *(unsigned*)&Bs[pxl * 48 + mt * 16 + q * 4 + r * 2] =
                    pack2f(acc[mt][nt][2 * r], acc[mt][nt][2 * r + 1]);
        }
    __syncthreads();

    const int h = bh >> 2, bb = bh & 3;
    const int pxl = t >> 1, half = t & 1;
    bf16* ob = pxT + ((size_t)bb * NPIX + px0 + pxl) * 768 + h * 48 + half * 24;
#pragma unroll
    for (int j = 0; j < 3; ++j)
        *(bf16x8*)(void*)(ob + j * 8) = *(const bf16x8*)&Bs[pxl * 48 + half * 24 + j * 8];
}

// ---------------------------------------------------------------------------
extern "C" void kernel_launch(void* const* d_in, const int* in_sizes, int n_in,
                              void* d_out, int out_size, void* d_ws, size_t ws_size,
                              hipStream_t stream) {
    const float* x       = (const float*)d_in[0];
    const float* w_qkv   = (const float*)d_in[1];
    const float* w_dw    = (const float*)d_in[2];
    const float* w_proj  = (const float*)d_in[3];
    const float* w_bs_pw = (const float*)d_in[4];
    const float* w_bs_dw = (const float*)d_in[5];
    float* out = (float*)d_out;
    bf16* y1 = (bf16*)d_out;  // bs_pw bf16 output lives in d_out space until proj

    const size_t SZQ = 150994944ull;  // 8h*4b*144*16384*2
    const size_t SZH = 18874368ull;   // 4b*144*16384*2
    const size_t SZY = 50331648ull;   // 4b*384*16384*2
    const size_t SZPXT = 100663296ull; // 4b*16384*768*2
    char* ws = (char*)d_ws;
    dim3 blk(256);

    if (ws_size >= 371404800ull) {
        // ---------- FULL: all heads batched ----------
        bf16* qkvp = (bf16*)ws;
        bf16* pxT  = (bf16*)ws;
        bf16* wprojp = (bf16*)(ws + SZPXT);
        float* Lbuf  = (float*)(ws + SZPXT + 1048576ull);  // dead-qkvp gap
        bf16* qkvd = (bf16*)(ws + SZQ);
        bf16* xT   = (bf16*)(ws + 2 * SZQ);
        bf16* yg   = xT;
        float* lp  = (float*)(ws + 2 * SZQ + SZY);
        bf16* wqkvp = (bf16*)lp;
        bf16* wbsp  = (bf16*)((char*)lp + 884736ull);
        bf16* abf  = (bf16*)(ws + 2 * SZQ + SZY + 18874368ull);
        float* inv = (float*)(ws + 2 * SZQ + SZY + 18874368ull + 196608ull);
        // sumsq in d_out tail (dead until final proj write; y1 uses only first 50MB)
        float* sumsq = (float*)((char*)d_out + 100663296ull - 16384ull);

        packw<<<dim3(216), blk, 0, stream>>>(w_qkv, wqkvp, 442368);
        packw<<<dim3(72), blk, 0, stream>>>(w_bs_pw, wbsp, 147456);
        xpose<<<dim3(256, 4), blk, 0, stream>>>(x, xT);
        gemm3<144, 384, bf16><<<dim3(4096), blk, 0, stream>>>(
            wqkvp, 48, 384, 48, xT, qkvp, 576, 144, 8, 4096);
        zerok<<<dim3(12), blk, 0, stream>>>(sumsq, 3072);
        dw3x3s<<<dim3(4, 1152, 4), blk, 0, stream>>>(
            qkvp, w_dw, qkvd, 1, 0, 144, 576, 144, 576, 0, 0, sumsq, 32);
        invk<<<dim3(12), blk, 0, stream>>>(sumsq, inv, 3072);
        packw<<<dim3(144), blk, 0, stream>>>(w_proj, wprojp, 294912);  // qkvp dead
        gemm3<128, 384, bf16><<<dim3(1536), blk, 0, stream>>>(
            wbsp, 128, 0, 128, xT, y1, 128, 384, 3, 1536);
        dw3x3s<<<dim3(4, 384, 4), blk, 0, stream>>>(
            y1, w_bs_dw, yg, 0, 0, 384, 0, 384, 0, 0, 1, nullptr, 0);  // xT dead
        xposeB<<<dim3(256, 4), blk, 0, stream>>>(yg, pxT);         // -> pxT[.., 384:768]
        qk_mfma<<<dim3(32, 16), blk, 0, stream>>>(qkvd, lp, 32, 256);
        logit_reduce<<<dim3(32 * 9), blk, 0, stream>>>(lp, inv, Lbuf, 32, 64);
        softmax48b<<<dim3(32), blk, 0, stream>>>(Lbuf, abf);
        av_mfma2<<<dim3(128, 32), blk, 0, stream>>>(abf, qkvd, pxT); // -> pxT[.., 0:384]
        gemm3<128, 768, float><<<dim3(1536), blk, 0, stream>>>(
            wprojp, 128, 0, 128, pxT, out, 128, 384, 3, 1536);
    } else if (ws_size >= 239284224ull) {
        // ---------- LITE: per-head pw+dw, rest batched ----------
        bf16* qkvd = (bf16*)ws;
        bf16* qph  = (bf16*)(ws + SZQ);
        bf16* yg   = (bf16*)(ws + SZQ + SZH);
        float* lp  = (float*)(ws + SZQ + SZH + SZY);
        bf16* abf  = (bf16*)(ws + SZQ + SZH + SZY + 18874368ull);
        float* inv = (float*)(ws + SZQ + SZH + SZY + 18874368ull + 196608ull);

        for (int h = 0; h < 8; ++h) {
            gemm48<float, bf16><<<dim3(3, 128, 4), blk, 0, stream>>>(
                x, x, 384, 384, 384, 0, 384, 384, 0, 384,
                w_qkv, 3, 384, 48, h * 48, qph, 3, 48, 0, 144, 0);
            dw3x3s<<<dim3(4, 144, 4), blk, 0, stream>>>(
                qph, w_dw, qkvd, 1, h * 48, 144, 0, 144, 0, h * 576, 0, nullptr, 0);
        }
        l2norm_v<<<dim3(2 * 32 * 48), blk, 0, stream>>>(qkvd, inv, 32);
        qk_mfma<<<dim3(32, 16), blk, 0, stream>>>(qkvd, lp, 32, 256);
        softmax48<<<dim3(32), blk, 0, stream>>>(lp, inv, abf, 32, 64);
        gemm48<float, bf16><<<dim3(8, 128, 4), blk, 0, stream>>>(
            x, x, 384, 384, 384, 0, 384, 384, 0, 384,
            w_bs_pw, 1, 0, 48, 0, y1, 1, 0, 48, 384, 0);
        dw3x3s<<<dim3(4, 384, 4), blk, 0, stream>>>(
            y1, w_bs_dw, yg, 0, 0, 384, 0, 384, 0, 0, 1, nullptr, 0);
        av_mfma<<<dim3(128, 32), blk, 0, stream>>>(abf, qkvd, qkvd, 0, 144);
        gemm48<bf16, float><<<dim3(8, 128, 4), blk, 0, stream>>>(
            qkvd, yg, 384, 768, 48, 576, 144, 384, 0, 384,
            w_proj, 1, 0, 48, 0, out, 1, 0, 48, 384, 0);
    } else {
        // ---------- ULTRA: fully per-head (~139.6 MB) ----------
        bf16* qph   = (bf16*)ws;
        bf16* qkvdh = (bf16*)(ws + SZH);
        bf16* yg    = (bf16*)(ws + 2 * SZH);
        bf16* attn  = (bf16*)(ws + 2 * SZH + SZY);
        float* lp   = (float*)(ws + 2 * SZH + 2 * SZY);
        bf16* abf   = (bf16*)(ws + 2 * SZH + 2 * SZY + 1179648ull);
        float* inv  = (float*)(ws + 2 * SZH + 2 * SZY + 1179648ull + 24576ull);

        gemm48<float, bf16><<<dim3(8, 128, 4), blk, 0, stream>>>(
            x, x, 384, 384, 384, 0, 384, 384, 0, 384,
            w_bs_pw, 1, 0, 48, 0, y1, 1, 0, 48, 384, 0);
        dw3x3s<<<dim3(4, 384, 4), blk, 0, stream>>>(
            y1, w_bs_dw, yg, 0, 0, 384, 0, 384, 0, 0, 1, nullptr, 0);
        for (int h = 0; h < 8; ++h) {
            gemm48<float, bf16><<<dim3(3, 128, 4), blk, 0, stream>>>(
                x, x, 384, 384, 384, 0, 384, 384, 0, 384,
                w_qkv, 3, 384, 48, h * 48, qph, 3, 48, 0, 144, 0);
            dw3x3s<<<dim3(4, 144, 4), blk, 0, stream>>>(
                qph, w_dw, qkvdh, 1, h * 48, 144, 0, 144, 0, 0, 0, nullptr, 0);
            l2norm_v<<<dim3(2 * 4 * 48), blk, 0, stream>>>(qkvdh, inv, 4);
            qk_mfma<<<dim3(4, 8), blk, 0, stream>>>(qkvdh, lp, 4, 512);
            softmax48<<<dim3(4), blk, 0, stream>>>(lp, inv, abf, 4, 32);
            av_mfma<<<dim3(128, 4), blk, 0, stream>>>(abf, qkvdh, attn, h * 48, 384);
        }
        gemm48<bf16, float><<<dim3(8, 128, 4), blk, 0, stream>>>(
            attn, yg, 384, 768, 384, 0, 384, 384, 0, 384,
            w_proj, 1, 0, 48, 0, out, 1, 0, 48, 384, 0);
    }
}